// Round 10
// baseline (1157.568 us; speedup 1.0000x reference)
//
#include <hip/hip_runtime.h>
#include <math.h>

// Problem constants
#define NTOT   8192
#define BGR    128
#define NPER   64
#define EDIR   65536
#define EKEEP  32768
#define EPSC   1e-5f

typedef unsigned short ushortT;
typedef __attribute__((ext_vector_type(8))) short bf16x8;
typedef __attribute__((ext_vector_type(4))) float f32x4;

// Operand dtype codes: 0 = bf16, 1 = f32, 2 = runtime (read *flagp)
#define C_BF 0
#define C_F32 1
#define C_RT 2

// ---------------- dtype helpers ----------------
__device__ __forceinline__ float bf2f(ushortT u) {
    union { unsigned int i; float f; } v; v.i = ((unsigned int)u) << 16; return v.f;
}
__device__ __forceinline__ ushortT f2bf(float f) {
    unsigned int u = __float_as_uint(f);
    u += 0x7FFFu + ((u >> 16) & 1u);   // round to nearest even
    return (ushortT)(u >> 16);
}
__device__ __forceinline__ float get1(const void* p, long i, int f) {
    return f ? ((const float*)p)[i] : bf2f(((const ushortT*)p)[i]);
}
__device__ __forceinline__ float ld1c(const float* p)   { return *p; }
__device__ __forceinline__ float ld1c(const ushortT* p) { return bf2f(*p); }
__device__ __forceinline__ void st1c(float* p, float v)   { *p = v; }
__device__ __forceinline__ void st1c(ushortT* p, float v) { *p = f2bf(v); }
__device__ __forceinline__ int clampi(int v, int lo, int hi) {
    return v < lo ? lo : (v > hi ? hi : v);
}

// direct global->LDS DMA, 16B per lane (lane-linear LDS destination required)
__device__ __forceinline__ void gld16(const void* g, void* l) {
    __builtin_amdgcn_global_load_lds(
        (const __attribute__((address_space(1))) unsigned int*)g,
        (__attribute__((address_space(3))) unsigned int*)l, 16, 0, 0);
}

// Bijective XCD-chunked block-id swizzle (m204).
__device__ __forceinline__ int xcd_swz(int flat, int nwg) {
    const int q = nwg >> 3, r = nwg & 7;
    const int xcd = flat & 7, idx = flat >> 3;
    return (xcd < r ? xcd * (q + 1) : r * (q + 1) + (xcd - r) * q) + idx;
}

// ---------------------------------------------------------------------------
// Float-input dtype detector (validated).
// ---------------------------------------------------------------------------
__launch_bounds__(256)
__global__ void detect_k(const unsigned int* __restrict__ xw, int* __restrict__ flag)
{
    __shared__ int red[256];
    const int t = threadIdx.x;
    int hits = 0;
#pragma unroll
    for (int i = 0; i < 4; ++i) {
        const unsigned w = xw[t*4 + i];
        const unsigned eb = (w >> 7) & 0xFF;
        hits += (eb >= 100 && eb <= 150) ? 1 : 0;
    }
    red[t] = hits; __syncthreads();
#pragma unroll
    for (int s = 128; s > 0; s >>= 1) { if (t < s) red[t] += red[t+s]; __syncthreads(); }
    if (t == 0) *flag = (red[0] < 512) ? 1 : 0;
}

// ---------------------------------------------------------------------------
// Fast bf16 GEMM (validated R7/R9): C = alpha*(A @ B^T) (+bias f32) (+C)
// (relu?). B stored [n][k]. 128x128 tile, 4 waves, 16x16x32 MFMA, BK=64,
// XOR-swizzled global_load_lds staging (SQ_LDS_BANK_CONFLICT==0 measured),
// XCD swizzle. 843 TF measured on the 32768x1536x1536 shapes.
// [R8 NOTE: 256^2 counted-vmcnt variant regressed (709 TF) — wait-ledger
//  mismatch; reverted. Do not re-attempt without the lead-7 derivation.]
// Requires M%128==0, N%128==0, K%64==0, lda/ldb%8==0.
// ---------------------------------------------------------------------------
template<class TC, bool BIAS, bool RESID, bool RELU>
__launch_bounds__(256)
__global__ void bgemm_k(const ushortT* __restrict__ A, const ushortT* __restrict__ B,
                        const float* __restrict__ bias, TC* __restrict__ C,
                        int K, int lda, int ldb, int ldc,
                        long sA, long sB, long sC, long biasOff, long bzStride,
                        float alpha)
{
    const int t = threadIdx.x;
    const int lane = t & 63, wave = t >> 6;
    const int l15 = lane & 15, quad = lane >> 4;
    const int wr = (wave >> 1) * 64, wc = (wave & 1) * 64;

    const int gx = gridDim.x, gy = gridDim.y;
    const int nwg = gx * gy * (int)gridDim.z;
    const int flat = xcd_swz(blockIdx.x + gx * (blockIdx.y + gy * blockIdx.z), nwg);
    const int bx = flat % gx;
    const int by = (flat / gx) % gy;
    const int bz = flat / (gx * gy);

    const int m0 = by * 128, n0 = bx * 128;
    const long z = bz;

    __shared__ __align__(16) ushortT As[128][64];
    __shared__ __align__(16) ushortT Bs[128][64];

    f32x4 acc[4][4] = {};

    const int sr = t >> 3;
    const int ssw = ((t & 7) ^ (sr & 7)) * 8;
    const ushortT* pA = A + z*sA + (long)(m0 + sr) * lda + ssw;
    const ushortT* pB = B + z*sB + (long)(n0 + sr) * ldb + ssw;
    ushortT* lA = &As[sr][(t & 7) * 8];
    ushortT* lB = &Bs[sr][(t & 7) * 8];

    for (int k0 = 0; k0 < K; k0 += 64) {
#pragma unroll
        for (int i = 0; i < 4; ++i) {
            gld16(pA + (long)i*32*lda + k0, lA + i*32*64);
            gld16(pB + (long)i*32*ldb + k0, lB + i*32*64);
        }
        __syncthreads();
#pragma unroll
        for (int kh = 0; kh < 2; ++kh) {
            const int ca = (kh*32 + quad*8) ^ ((l15 & 7) * 8);
            bf16x8 af[4], bfr[4];
#pragma unroll
            for (int i = 0; i < 4; ++i) {
                af[i]  = *(const bf16x8*)&As[wr + i*16 + l15][ca];
                bfr[i] = *(const bf16x8*)&Bs[wc + i*16 + l15][ca];
            }
#pragma unroll
            for (int mt = 0; mt < 4; ++mt)
#pragma unroll
                for (int nt = 0; nt < 4; ++nt)
                    acc[mt][nt] = __builtin_amdgcn_mfma_f32_16x16x32_bf16(af[mt], bfr[nt], acc[mt][nt], 0, 0, 0);
        }
        __syncthreads();
    }

    TC* Cb = C + z * sC;
#pragma unroll
    for (int nt = 0; nt < 4; ++nt) {
        const int col = n0 + wc + nt*16 + l15;
        const float bv = BIAS ? bias[biasOff + z*bzStride + col] : 0.f;
#pragma unroll
        for (int mt = 0; mt < 4; ++mt) {
#pragma unroll
            for (int r = 0; r < 4; ++r) {
                const int row = m0 + wr + mt*16 + quad*4 + r;
                TC* cp = Cb + (long)row * ldc + col;
                float val = alpha * acc[mt][nt][r] + bv;
                if constexpr (RESID) val += ld1c(cp);
                if constexpr (RELU)  val = fmaxf(val, 0.f);
                st1c(cp, val);
            }
        }
    }
}

// ---------------------------------------------------------------------------
// R10: fused S-gemm + row softmax. Per block: 64 edge rows x FULL 256 cols of
// one batch: S = alpha*(T_b @ F_b^T) + bvec[col], then row softmax, writing
// bf16 P directly into S_c's ushort layout (row*512, batch stride 131072).
// Replaces the separate S-bgemm + softmax_ip_k (kills 67 MB of f32 S traffic
// + one dispatch). Epilogue: per-quad shfl_xor reduce (16 lanes share a row)
// + fixed-order cross-wave LDS combine — deterministic.
// ---------------------------------------------------------------------------
__launch_bounds__(256)
__global__ void sgemm_sm_k(const ushortT* __restrict__ A, const ushortT* __restrict__ B,
                           const float* __restrict__ bvec, float* __restrict__ S,
                           float alpha)
{
    const int t = threadIdx.x;
    const int lane = t & 63, wave = t >> 6;   // wave = column-panel index
    const int l15 = lane & 15, quad = lane >> 4;

    const int gx = gridDim.x;                 // 4 row-blocks of 64
    const int nwg = gx * (int)gridDim.y;
    const int flat = xcd_swz(blockIdx.x + gx * blockIdx.y, nwg);
    const int rb = flat % gx;
    const int z  = flat / gx;

    const int m0 = rb * 64;

    __shared__ __align__(16) ushortT As[64][64];
    __shared__ __align__(16) ushortT Bs[256][64];
    __shared__ float redA[4][64];
    __shared__ float redB[4][64];

    f32x4 acc[4][4] = {};

    const int sr = t >> 3;                    // 0..31 (32 rows per issue)
    const int ssw = ((t & 7) ^ (sr & 7)) * 8;
    const ushortT* pA = A + (long)z*256*1536 + (long)(m0 + sr) * 1536 + ssw;
    const ushortT* pB = B + (long)z*256*1536 + (long)sr * 1536 + ssw;
    ushortT* lA = &As[sr][(t & 7) * 8];
    ushortT* lB = &Bs[sr][(t & 7) * 8];

    for (int k0 = 0; k0 < 1536; k0 += 64) {
        gld16(pA + k0, lA);
        gld16(pA + 32L*1536 + k0, lA + 32*64);
#pragma unroll
        for (int i = 0; i < 8; ++i)
            gld16(pB + (long)i*32*1536 + k0, lB + i*32*64);
        __syncthreads();
#pragma unroll
        for (int kh = 0; kh < 2; ++kh) {
            const int ca = (kh*32 + quad*8) ^ ((l15 & 7) * 8);
            bf16x8 af[4], bfr[4];
#pragma unroll
            for (int i = 0; i < 4; ++i) {
                af[i]  = *(const bf16x8*)&As[i*16 + l15][ca];
                bfr[i] = *(const bf16x8*)&Bs[wave*64 + i*16 + l15][ca];
            }
#pragma unroll
            for (int mt = 0; mt < 4; ++mt)
#pragma unroll
                for (int nt = 0; nt < 4; ++nt)
                    acc[mt][nt] = __builtin_amdgcn_mfma_f32_16x16x32_bf16(af[mt], bfr[nt], acc[mt][nt], 0, 0, 0);
        }
        __syncthreads();
    }

    float bv[4];
#pragma unroll
    for (int nt = 0; nt < 4; ++nt)
        bv[nt] = bvec[z*256 + wave*64 + nt*16 + l15];

    // pass 1: per-row max (64 cols in-wave, then cross-wave via LDS)
#pragma unroll
    for (int mt = 0; mt < 4; ++mt) {
#pragma unroll
        for (int r = 0; r < 4; ++r) {
            float m = -3.4e38f;
#pragma unroll
            for (int nt = 0; nt < 4; ++nt)
                m = fmaxf(m, alpha * acc[mt][nt][r] + bv[nt]);
#pragma unroll
            for (int sh = 1; sh < 16; sh <<= 1)
                m = fmaxf(m, __shfl_xor(m, sh));
            if (l15 == 0) redA[wave][mt*16 + quad*4 + r] = m;
        }
    }
    __syncthreads();
    // pass 2: exp + row sum (exp overwrites acc)
#pragma unroll
    for (int mt = 0; mt < 4; ++mt) {
#pragma unroll
        for (int r = 0; r < 4; ++r) {
            const int lr = mt*16 + quad*4 + r;
            const float mx = fmaxf(fmaxf(redA[0][lr], redA[1][lr]),
                                   fmaxf(redA[2][lr], redA[3][lr]));
            float s = 0.f;
#pragma unroll
            for (int nt = 0; nt < 4; ++nt) {
                const float e = __expf(alpha * acc[mt][nt][r] + bv[nt] - mx);
                acc[mt][nt][r] = e;
                s += e;
            }
#pragma unroll
            for (int sh = 1; sh < 16; sh <<= 1)
                s += __shfl_xor(s, sh);
            if (l15 == 0) redB[wave][lr] = s;
        }
    }
    __syncthreads();
    // pass 3: normalize + write bf16 P (row*512 ushorts, batch stride 131072)
    ushortT* P = (ushortT*)S + (long)z*131072 + (long)m0*512;
#pragma unroll
    for (int mt = 0; mt < 4; ++mt) {
#pragma unroll
        for (int r = 0; r < 4; ++r) {
            const int lr = mt*16 + quad*4 + r;
            const float den = redB[0][lr] + redB[1][lr] + redB[2][lr] + redB[3][lr];
            const float inv = 1.f / den;
#pragma unroll
            for (int nt = 0; nt < 4; ++nt)
                P[(long)lr*512 + wave*64 + nt*16 + l15] = f2bf(acc[mt][nt][r] * inv);
        }
    }
}

// ---------------- block reduction (256 threads) ----------------
__device__ __forceinline__ float blockReduceSum(float v, float* red, int t)
{
    red[t] = v; __syncthreads();
#pragma unroll
    for (int s = 128; s > 0; s >>= 1) {
        if (t < s) red[t] += red[t + s];
        __syncthreads();
    }
    const float r = red[0];
    __syncthreads();
    return r;
}

// ---------------------------------------------------------------------------
// Weight convert / transpose-convert to bf16 fast-path layouts.
// ---------------------------------------------------------------------------
__launch_bounds__(256)
__global__ void convbf_k(const void* __restrict__ in, ushortT* __restrict__ out,
                         long n4, const int* __restrict__ flagp)
{
    const int f = *flagp;
    const long i = (long)blockIdx.x*256 + threadIdx.x;
    if (i >= n4) return;
    const long i0 = i * 4;
    if (f) {
        const float4 v = *(const float4*)((const float*)in + i0);
        ushort4 o; o.x=f2bf(v.x); o.y=f2bf(v.y); o.z=f2bf(v.z); o.w=f2bf(v.w);
        *(ushort4*)(out + i0) = o;
    } else {
        *(ushort4*)(out + i0) = *(const ushort4*)((const ushortT*)in + i0);
    }
}

// R10: 4-way batched 1536x1536 transpose-convert (z selects src/dst pair)
__launch_bounds__(256)
__global__ void tconvbf4_k(const void* __restrict__ i0, const void* __restrict__ i1,
                           const void* __restrict__ i2, const void* __restrict__ i3,
                           ushortT* __restrict__ o0, ushortT* __restrict__ o1,
                           ushortT* __restrict__ o2, ushortT* __restrict__ o3,
                           const int* __restrict__ flagp)
{
    const int f = *flagp;
    const void* in; ushortT* out;
    switch (blockIdx.z) {
        case 0:  in = i0; out = o0; break;
        case 1:  in = i1; out = o1; break;
        case 2:  in = i2; out = o2; break;
        default: in = i3; out = o3; break;
    }
    __shared__ float tile[32][33];
    const int bx = blockIdx.x, by = blockIdx.y;
    const int tx = threadIdx.x & 31, ty = threadIdx.x >> 5;
#pragma unroll
    for (int i = 0; i < 4; ++i) {
        const int k = by*32 + ty + i*8;
        tile[ty + i*8][tx] = get1(in, (long)k*1536 + bx*32 + tx, f);
    }
    __syncthreads();
#pragma unroll
    for (int i = 0; i < 4; ++i) {
        const int n = bx*32 + ty + i*8;
        out[(long)n*1536 + by*32 + tx] = f2bf(tile[tx][ty + i*8]);
    }
}

// R9: transpose-convert [256][512] k-major weight into Wg2T[n][512] at column
// offset koff (fused-gconv2 B operand).
__launch_bounds__(256)
__global__ void tconv512_k(const void* __restrict__ in, ushortT* __restrict__ out,
                           int koff, const int* __restrict__ flagp)
{
    const int f = *flagp;
    __shared__ float tile[32][33];
    const int bx = blockIdx.x, by = blockIdx.y;
    const int tx = threadIdx.x & 31, ty = threadIdx.x >> 5;
#pragma unroll
    for (int i = 0; i < 4; ++i) {
        const int k = by*32 + ty + i*8;
        tile[ty + i*8][tx] = get1(in, (long)k*512 + bx*32 + tx, f);
    }
    __syncthreads();
#pragma unroll
    for (int i = 0; i < 4; ++i) {
        const int n = bx*32 + ty + i*8;
        out[(long)n*512 + koff + by*32 + tx] = f2bf(tile[tx][ty + i*8]);
    }
}

__launch_bounds__(256)
__global__ void convf32_k(const void* __restrict__ in, float* __restrict__ out,
                          int n, const int* __restrict__ flagp)
{
    const int f = *flagp;
    const int i = blockIdx.x*256 + threadIdx.x;
    if (i < n) out[i] = get1(in, i, f);
}

// ---------------------------------------------------------------------------
// colcomb split (validated): partials + deterministic reduce.
// ---------------------------------------------------------------------------
__launch_bounds__(256)
__global__ void colcomb_part_k(const void* __restrict__ v, int cv, long voff,
                               const void* __restrict__ W, int cW,
                               float* __restrict__ part, const int* __restrict__ flagp)
{
    const int rtf = *flagp;
    const int fv = (cv == C_RT) ? rtf : cv;
    const int fW = (cW == C_RT) ? rtf : cW;
    const int d = blockIdx.x*256 + threadIdx.x;
    const int c0 = blockIdx.y * 24;
    float a = 0.f;
#pragma unroll
    for (int i = 0; i < 24; ++i) {
        const int c = c0 + i;
        a += get1(v, voff + c, fv) * get1(W, (long)c*1536 + d, fW);
    }
    part[blockIdx.y * 1536 + d] = a;
}

__launch_bounds__(256)
__global__ void colcomb_red_k(const float* __restrict__ part,
                              const void* __restrict__ b, int cb,
                              float* __restrict__ out, const int* __restrict__ flagp)
{
    const int rtf = *flagp;
    const int fb = (cb == C_RT) ? rtf : cb;
    const int d = blockIdx.x*256 + threadIdx.x;
    float a = get1(b, d, fb);
#pragma unroll 8
    for (int cy = 0; cy < 64; ++cy) a += part[cy*1536 + d];
    out[d] = a;
}

// ---------------------------------------------------------------------------
// rowdot: out[r] = scale * sum_c bf2f(W[r*1536+c]) * v[c]
// ---------------------------------------------------------------------------
__launch_bounds__(256)
__global__ void rowdot_k(const ushortT* __restrict__ W, const float* __restrict__ v,
                         float* __restrict__ out, float scale)
{
    const int r = blockIdx.x, t = threadIdx.x;
    __shared__ float red[256];
    float p = 0.f;
    for (int c = t; c < 1536; c += 256) p += bf2f(W[(long)r*1536 + c]) * v[c];
    const float tot = blockReduceSum(p, red, t);
    if (t == 0) out[r] = scale * tot;
}

// ---------------------------------------------------------------------------
// gconv1 fused (validated; R10: node loop split across blockIdx.y (2x blocks)
// — bucketing preamble duplicated, serial 64-node loops halved)
// ---------------------------------------------------------------------------
__launch_bounds__(256)
__global__ void gconv1_k(int b0, const void* __restrict__ x, const int* __restrict__ edges,
                         const void* __restrict__ ea,
                         const void* __restrict__ wembW, const void* __restrict__ wembB,
                         const void* __restrict__ Wrel, const void* __restrict__ brel,
                         const void* __restrict__ Wroot, ushortT* __restrict__ ah,
                         const int* __restrict__ flagp)
{
    const int f = *flagp;
    const int bl = blockIdx.x, g = b0 + bl, t = threadIdx.x;
    const int nb0 = blockIdx.y * 32;
    __shared__ float s_x[64][5];
    __shared__ float s_agg[64][5];
    __shared__ int   s_cnt[64];
    __shared__ int   s_off[65];
    __shared__ int   s_src[512];
    __shared__ float s_w[512];

    if (t < 64) s_cnt[t] = 0;
    if (t < 320) s_x[t/5][t%5] = get1(x, (long)(g*64 + t/5)*5 + (t%5), f);
    __syncthreads();

    const float w0 = get1(wembW,0,f), w1 = get1(wembW,1,f), w2 = get1(wembW,2,f);
    const float wb = get1(wembB,0,f);
    int sl[2], dl[2], slot[2]; float wv[2];
#pragma unroll
    for (int e2 = 0; e2 < 2; ++e2) {
        const int e = g*512 + t + 256*e2;
        const int s = edges[e], d = edges[EDIR + e];
        sl[e2] = clampi(s - g*64, 0, 63); dl[e2] = clampi(d - g*64, 0, 63);
        const float a0 = get1(ea, 2L*e, f), a1 = get1(ea, 2L*e+1, f);
        wv[e2] = fmaxf(a0*w0 + ((a1 < 0.5f) ? w1 : w2) + wb, 0.f);
        slot[e2] = atomicAdd(&s_cnt[dl[e2]], 1);
    }
    __syncthreads();
    if (t == 0) {
        int r = 0;
        for (int i = 0; i < 64; ++i) { s_off[i] = r; r += s_cnt[i]; }
        s_off[64] = r;
    }
    __syncthreads();
#pragma unroll
    for (int e2 = 0; e2 < 2; ++e2) {
        const int p = s_off[dl[e2]] + slot[e2];
        s_src[p] = sl[e2]; s_w[p] = wv[e2];
    }
    __syncthreads();
    if (t < 160) {
        const int n = nb0 + t/5, k = t%5;
        float acc = 0.f;
        for (int i = s_off[n]; i < s_off[n+1]; ++i) acc += s_w[i] * s_x[s_src[i]][k];
        s_agg[n][k] = acc;
    }
    __syncthreads();
    float wr[5], wo[5];
#pragma unroll
    for (int k = 0; k < 5; ++k) { wr[k] = get1(Wrel, k*256 + t, f); wo[k] = get1(Wroot, k*256 + t, f); }
    const float bb = get1(brel, t, f);
    for (int n = nb0; n < nb0 + 32; ++n) {
        float v = bb;
#pragma unroll
        for (int k = 0; k < 5; ++k) v += s_agg[n][k]*wr[k] + s_x[n][k]*wo[k];
        ah[(long)(bl*64 + n)*512 + 256 + t] = f2bf(fmaxf(v, 0.f));
    }
}

// ---------------------------------------------------------------------------
// gconv2 aggregation (validated; R10: node loop split across blockIdx.y)
// ---------------------------------------------------------------------------
__launch_bounds__(256)
__global__ void gconv2_agg_k(int b0, ushortT* __restrict__ ah, const int* __restrict__ edges,
                             const void* __restrict__ ea,
                             const void* __restrict__ wembW, const void* __restrict__ wembB,
                             const int* __restrict__ flagp)
{
    const int f = *flagp;
    const int bl = blockIdx.x, g = b0 + bl, t = threadIdx.x;
    const int nb0 = blockIdx.y * 32;
    __shared__ int   s_cnt[64];
    __shared__ int   s_off[65];
    __shared__ int   s_src[512];
    __shared__ float s_w[512];

    if (t < 64) s_cnt[t] = 0;
    __syncthreads();

    const float w0 = get1(wembW,0,f), w1 = get1(wembW,1,f), w2 = get1(wembW,2,f);
    const float wb = get1(wembB,0,f);
    int sl[2], dl[2], slot[2]; float wv[2];
#pragma unroll
    for (int e2 = 0; e2 < 2; ++e2) {
        const int e = g*512 + t + 256*e2;
        const int s = edges[e], d = edges[EDIR + e];
        sl[e2] = clampi(s - g*64, 0, 63); dl[e2] = clampi(d - g*64, 0, 63);
        const float a0 = get1(ea, 2L*e, f), a1 = get1(ea, 2L*e+1, f);
        wv[e2] = fmaxf(a0*w0 + ((a1 < 0.5f) ? w1 : w2) + wb, 0.f);
        slot[e2] = atomicAdd(&s_cnt[dl[e2]], 1);
    }
    __syncthreads();
    if (t == 0) {
        int r = 0;
        for (int i = 0; i < 64; ++i) { s_off[i] = r; r += s_cnt[i]; }
        s_off[64] = r;
    }
    __syncthreads();
#pragma unroll
    for (int e2 = 0; e2 < 2; ++e2) {
        const int p = s_off[dl[e2]] + slot[e2];
        s_src[p] = sl[e2]; s_w[p] = wv[e2];
    }
    __syncthreads();
    for (int n = nb0; n < nb0 + 32; ++n) {
        float acc = 0.f;
        const int i0 = s_off[n], i1 = s_off[n+1];
        for (int i = i0; i < i1; ++i)
            acc += s_w[i] * bf2f(ah[(long)(bl*64 + s_src[i])*512 + 256 + t]);
        ah[(long)(bl*64 + n)*512 + t] = f2bf(acc);
    }
}

// ---------------------------------------------------------------------------
// GraphNorm (validated; split across blockIdx.y)
// ---------------------------------------------------------------------------
__launch_bounds__(256)
__global__ void gnorm_k(ushortT* __restrict__ h, const void* __restrict__ gw,
                        const void* __restrict__ gb, const void* __restrict__ gms,
                        const int* __restrict__ flagp)
{
    const int f0 = *flagp;
    const int bl = blockIdx.x, t = threadIdx.x;
    const int f = t + 256*blockIdx.y;
    float acc = 0.f;
    for (int n = 0; n < 64; ++n) acc += bf2f(h[(bl*64+n)*512 + f]);
    const float m2 = get1(gms, f, f0) * (acc * (1.f/64.f));
    float v = 0.f;
    for (int n = 0; n < 64; ++n) { const float d = bf2f(h[(bl*64+n)*512 + f]) - m2; v += d*d; }
    const float rs = rsqrtf(v*(1.f/64.f) + EPSC);
    const float g = get1(gw, f, f0), bb = get1(gb, f, f0);
    for (int n = 0; n < 64; ++n) {
        const int idx = (bl*64+n)*512 + f;
        h[idx] = f2bf(g * (bf2f(h[idx]) - m2) * rs + bb);
    }
}

// ---------------------------------------------------------------------------
// SplitSyndromes sort (unchanged — validated)
// ---------------------------------------------------------------------------
__launch_bounds__(256)
__global__ void sort_k(const int* __restrict__ edges, int* __restrict__ sorted_orig,
                       int* __restrict__ se, int* __restrict__ te)
{
    const int b = blockIdx.x, t = threadIdx.x;
    __shared__ int s_keep[512];
    __shared__ int s_key[512];
    __shared__ int s_ckey[256];
    __shared__ int s_corig[256];
#pragma unroll
    for (int e2 = 0; e2 < 2; ++e2) {
        const int el = t + 256*e2;
        const int e = b*512 + el;
        const int s = edges[e], d = edges[EDIR + e];
        s_keep[el] = (s > d) ? 1 : 0;
        s_key[el]  = ((s - b*64) << 6) | (d - b*64);
    }
    __syncthreads();
#pragma unroll
    for (int e2 = 0; e2 < 2; ++e2) {
        const int el = t + 256*e2;
        if (s_keep[el]) {
            int pos = 0;
            for (int j = 0; j < el; ++j) pos += s_keep[j];
            s_ckey[pos]  = s_key[el];
            s_corig[pos] = b*512 + el;
        }
    }
    __syncthreads();
    const int ki = s_ckey[t];
    int rank = 0;
    for (int j = 0; j < 256; ++j) {
        const int kj = s_ckey[j];
        rank += (kj < ki || (kj == ki && j < t)) ? 1 : 0;
    }
    const int orig = s_corig[t];
    const int p = b*256 + rank;
    sorted_orig[p] = orig;
    se[p] = edges[orig];
    te[p] = edges[EDIR + orig];
}

// ---------------------------------------------------------------------------
// Build F_c + bvec[ge] = F[e] . kb  (unchanged — validated)
// ---------------------------------------------------------------------------
__launch_bounds__(256)
__global__ void fbuild_k(int b0, int maxn, const ushortT* __restrict__ h,
                         const int* __restrict__ sorted_orig,
                         const int* __restrict__ se, const int* __restrict__ te,
                         const void* __restrict__ ea,
                         const void* __restrict__ eW, const void* __restrict__ eB,
                         const float* __restrict__ kb,
                         ushortT* __restrict__ F, float* __restrict__ bvec,
                         const int* __restrict__ flagp)
{
    const int fl = *flagp;
    const int e = blockIdx.x, t = threadIdx.x;
    __shared__ float red[256];
    const int ge = b0*256 + e;
    const int s = clampi(se[ge] - b0*64, 0, maxn);
    const int d = clampi(te[ge] - b0*64, 0, maxn);
    const int orig = clampi(sorted_orig[ge], 0, EDIR-1);
    const float a0 = get1(ea, 2L*orig, fl), a1 = get1(ea, 2L*orig + 1, fl);
    float partial = 0.f;
#pragma unroll
    for (int c = 0; c < 6; ++c) {
        const int col = c*256 + t;
        float v;
        if (c < 2) {
            v = bf2f(h[(long)s*512 + col]);
        } else if (c < 4) {
            const int ff = col - 512;
            v = fmaxf(a0*get1(eW, ff, fl)
                      + ((a1 < 0.5f) ? get1(eW, 512+ff, fl) : get1(eW, 1024+ff, fl))
                      + get1(eB, ff, fl), 0.f);
        } else {
            v = bf2f(h[(long)d*512 + (col - 1024)]);
        }
        F[(long)e*1536 + col] = f2bf(v);
        partial += v * kb[col];
    }
    const float tot = blockReduceSum(partial, red, t);
    if (t == 0) bvec[ge] = tot;
}

// ---------------------------------------------------------------------------
// fused LayerNorm + head dot (R10: vectorized bf16x8 loads, t<192 active)
// ---------------------------------------------------------------------------
__launch_bounds__(256)
__global__ void ln_head_k(int b0, const ushortT* __restrict__ F, const void* __restrict__ lng,
                          const void* __restrict__ lnb, const void* __restrict__ hW,
                          const void* __restrict__ hB, float* __restrict__ gout,
                          const int* __restrict__ flagp)
{
    const int fl = *flagp;
    const int e = blockIdx.x, t = threadIdx.x;
    __shared__ float red[256];
    const bool act = t < 192;
    float xv[8];
    float s = 0.f;
    if (act) {
        const bf16x8 v = *(const bf16x8*)&F[(long)e*1536 + t*8];
#pragma unroll
        for (int j = 0; j < 8; ++j) { xv[j] = bf2f((ushortT)v[j]); s += xv[j]; }
    } else {
#pragma unroll
        for (int j = 0; j < 8; ++j) xv[j] = 0.f;
    }
    const float tot = blockReduceSum(s, red, t);
    const float mu = tot * (1.f/1536.f);
    float ss = 0.f;
    if (act) {
#pragma unroll
        for (int j = 0; j < 8; ++j) { const float d = xv[j] - mu; ss += d*d; }
    }
    const float tot2 = blockReduceSum(ss, red, t);
    const float rs = rsqrtf(tot2 * (1.f/1536.f) + EPSC);
    float p = 0.f;
    if (act) {
#pragma unroll
        for (int j = 0; j < 8; ++j) {
            const int col = t*8 + j;
            p += (get1(lng, col, fl) * (xv[j] - mu) * rs + get1(lnb, col, fl)) * get1(hW, col, fl);
        }
    }
    const float tot3 = blockReduceSum(p, red, t);
    if (t == 0) gout[b0*256 + e] = tot3 + get1(hB, 0, fl);
}

// ---------------- final output assembly (unchanged — validated) -------------
__launch_bounds__(128)
__global__ void final_k(const float* __restrict__ gout, const int* __restrict__ se,
                        const int* __restrict__ te, const int* __restrict__ sorted_orig,
                        const void* __restrict__ ea, float* __restrict__ out,
                        const int* __restrict__ flagp)
{
    const int fl = *flagp;
    const int b = blockIdx.x, j = threadIdx.x;
    const int e0 = b*256 + 2*j, e1 = e0 + 1;
    const float p0 = gout[e0], p1 = gout[e1];
    const int idx = (p1 < p0) ? 1 : 0;
    const float val = idx ? p1 : p0;
    const int eo = idx ? e1 : e0;
    const int orig = clampi(sorted_orig[eo], 0, EDIR-1);
    const float cls = get1(ea, 2L*orig + 1, fl);
    out[(b*128 + j)*2 + 0] = (float)se[e0];
    out[(b*128 + j)*2 + 1] = (float)te[e0];
    out[32768 + b*128 + j] = val;
    out[32768 + 16384 + b*128 + j] = cls;
}

// ---------------------------------------------------------------------------
// Launch. R10: fused S-gemm+softmax (sgemm_sm_k) replaces S-bgemm +
// softmax_ip_k; gconv1/gconv2_agg node-split (2x blocks); ln_head vectorized;
// 4 tconvbf batched into one dispatch. Big GEMMs unchanged (validated 843 TF).
// ---------------------------------------------------------------------------
extern "C" void kernel_launch(void* const* d_in, const int* in_sizes, int n_in,
                              void* d_out, int out_size, void* d_ws, size_t ws_size,
                              hipStream_t stream)
{
    (void)out_size;

    const void* x     = d_in[0];
    const int*  edges = (const int*)d_in[1];
    const void* ea    = d_in[2];

    int ws0 = 3;
    while (ws0 < n_in && in_sizes[ws0] != 3) ++ws0;
    if (ws0 + 27 > n_in) ws0 = 5;

    const void* wembW  = d_in[ws0 + 0];
    const void* wembB  = d_in[ws0 + 1];
    const void* g1Wrel = d_in[ws0 + 2];
    const void* g1brel = d_in[ws0 + 3];
    const void* g1Wroot= d_in[ws0 + 4];
    const void* g2Wrel = d_in[ws0 + 5];
    const void* g2brel = d_in[ws0 + 6];
    const void* g2Wroot= d_in[ws0 + 7];
    const void* gnw    = d_in[ws0 + 8];
    const void* gnb    = d_in[ws0 + 9];
    const void* gnms   = d_in[ws0 + 10];
    const void* eembW  = d_in[ws0 + 11];
    const void* eembB  = d_in[ws0 + 12];
    const void* qkvW   = d_in[ws0 + 13];
    const void* qkvb   = d_in[ws0 + 14];
    const void* inWq   = d_in[ws0 + 15];
    const void* inWk   = d_in[ws0 + 16];
    const void* inWv   = d_in[ws0 + 17];
    const void* inbq   = d_in[ws0 + 18];
    // inbk (ws0+19): row-constant score terms -> drop in softmax
    const void* inbv   = d_in[ws0 + 20];
    const void* outW   = d_in[ws0 + 21];
    const void* outb   = d_in[ws0 + 22];
    const void* lng    = d_in[ws0 + 23];
    const void* lnb    = d_in[ws0 + 24];
    const void* headW  = d_in[ws0 + 25];
    const void* headb  = d_in[ws0 + 26];

    char* ws = (char*)d_ws;
    size_t off = 0;
    auto alloc = [&](size_t bytes) {
        void* p = ws + off;
        off = (off + bytes + 255) & ~(size_t)255;
        return p;
    };
    // ---- fixed region (~12 MB) ----
    int*     dflag  = (int*)    alloc(256);
    float*   gout   = (float*)  alloc(EKEEP*4);
    int*     sorted = (int*)    alloc(EKEEP*4);
    int*     seg    = (int*)    alloc(EKEEP*4);
    int*     teg    = (int*)    alloc(EKEEP*4);
    float*   bvec   = (float*)  alloc(EKEEP*4);
    float*   bqc    = (float*)  alloc(1536*4);
    float*   bvc    = (float*)  alloc(1536*4);
    float*   kb     = (float*)  alloc(1536*4);
    float*   bvo    = (float*)  alloc(1536*4);
    float*   g2bf   = (float*)  alloc(512*4);
    float*   colpart= (float*)  alloc(64L*1536*4);
    ushortT* Wg2T   = (ushortT*)alloc(512L*512*2);     // fused gconv2 B, [n][k]
    ushortT* MpWv   = (ushortT*)alloc(2L*1536*1536*2); // [Mp^T ; Wvo] contiguous
    ushortT* MpT    = MpWv;                            // Mp^T, [n][k]
    ushortT* Wvo    = MpWv + 1536L*1536;               // Wvo, ROW-major [m][k]
    const size_t fixedB = off;

    // ---- union region (phase-W scratch; overlaps chunk scratch) ----
    const long W2 = 1536L * 1536;
    ushortT* Wqc    = (ushortT*)(ws + fixedB);
    ushortT* Wkc    = Wqc + W2;
    ushortT* Wvc    = Wqc + 2*W2;
    ushortT* outWT  = Wqc + 3*W2;
    ushortT* qkvWbf = Wqc + 4*W2;     // 1536x4608
    ushortT* inWqT  = Wqc + 7*W2;
    ushortT* inWkT  = Wqc + 8*W2;     // adjacent (z=3 B stride = W2)
    ushortT* inWvT  = Wqc + 9*W2;

    // ---- chunk scratch (G=128 guaranteed: perG = 1.97 MB -> ~252 MB) ----
    const size_t perG = 64L*512*2 + 64L*512*2 + 2L*256*1536*2 + 256L*256*4;
    int G = 128;
    while (G > 2 && fixedB + (size_t)G*perG + 65536 > ws_size) G >>= 1;

    size_t coff = fixedB;
    auto calloc2 = [&](size_t bytes) {
        void* p = ws + coff;
        coff = (coff + bytes + 255) & ~(size_t)255;
        return p;
    };
    ushortT* h_c  = (ushortT*)calloc2((size_t)G*64*512*2);
    ushortT* ah_c = (ushortT*)calloc2((size_t)G*64*512*2);   // [ag | h1] K=512
    ushortT* F_c  = (ushortT*)calloc2((size_t)G*256*1536*2);
    ushortT* T_c  = (ushortT*)calloc2((size_t)G*256*1536*2); // T, then V'^T
    float*   S_c  = (float*)  calloc2((size_t)G*256*256*4);  // bf16 P lives here

    const float scale = 0.02551551815399144f;  // 1/sqrt(1536)
    const dim3 blk(256);

    detect_k<<<1, blk, 0, stream>>>((const unsigned int*)x, dflag);
    sort_k<<<128, blk, 0, stream>>>(edges, sorted, seg, teg);

    // ---- phase W ----
    convbf_k<<<(1536*4608/4 + 255)/256, blk, 0, stream>>>(qkvW, qkvWbf, 1536L*4608/4, dflag);
    tconvbf4_k<<<dim3(48,48,4), blk, 0, stream>>>(inWq, inWk, inWv, outW,
                                                  inWqT, inWkT, inWvT, outWT, dflag);
    tconv512_k<<<dim3(16,8), blk, 0, stream>>>(g2Wrel, Wg2T, 0, dflag);
    tconv512_k<<<dim3(16,8), blk, 0, stream>>>(g2Wroot, Wg2T, 256, dflag);
    convf32_k<<<2, blk, 0, stream>>>(g2brel, g2bf, 512, dflag);
    // (Wqc,Wkc,Wvc) z=3 batch: A = qkvWbf k-slices (sA=1536), B = inW{q,k,v}T
    bgemm_k<ushortT,false,false,false><<<dim3(12,12,3), blk, 0, stream>>>(
        qkvWbf, inWqT, nullptr, Wqc, 1536, 4608, 1536, 1536,
        1536L, W2, W2, 0, 0, 1.f);
    colcomb_part_k<<<dim3(6,64), blk, 0, stream>>>(qkvb, C_RT, 0, inWq, C_RT, colpart, dflag);
    colcomb_red_k<<<6, blk, 0, stream>>>(colpart, inbq, C_RT, bqc, dflag);
    // kb = scale * Wkc @ bqc
    rowdot_k<<<1536, blk, 0, stream>>>(Wkc, bqc, kb, scale);
    colcomb_part_k<<<dim3(6,64), blk, 0, stream>>>(qkvb, C_RT, 3072, inWv, C_RT, colpart, dflag);
    colcomb_red_k<<<6, blk, 0, stream>>>(colpart, inbv, C_RT, bvc, dflag);
    // (MpT, Wvo) z=2 batch, unscaled (scale lives in the S-gemm alpha):
    //   z=0: MpT = Wkc @ Wqc^T
    //   z=1: Wvo = Wvc @ outWT^T = Wvc @ outW   (row-major Wvo)
    bgemm_k<ushortT,false,false,false><<<dim3(12,12,2), blk, 0, stream>>>(
        Wkc, Wqc, nullptr, MpT, 1536, 1536, 1536, 1536,
        W2, 3*W2, W2, 0, 0, 1.f);
    colcomb_part_k<<<dim3(6,64), blk, 0, stream>>>(bvc, C_F32, 0, outW, C_RT, colpart, dflag);
    colcomb_red_k<<<6, blk, 0, stream>>>(colpart, outb, C_RT, bvo, dflag);

    // ---- per-chunk pipeline ----
    const int nchunk = 128 / G;
    const int EC = G * 256;
    for (int c = 0; c < nchunk; ++c) {
        const int b0 = c * G;
        const int maxn = G*64 - 1;
        gconv1_k<<<dim3(G,2), blk, 0, stream>>>(b0, x, edges, ea, wembW, wembB,
                                                g1Wrel, g1brel, g1Wroot, ah_c, dflag);
        gconv2_agg_k<<<dim3(G,2), blk, 0, stream>>>(b0, ah_c, edges, ea, wembW, wembB, dflag);
        // h = relu([ag|h1] @ Wg2T^T + g2b)   (fused gconv2, K=512)
        bgemm_k<ushortT,true,false,true><<<dim3(4, G/2, 1), blk, 0, stream>>>(
            ah_c, Wg2T, g2bf, h_c, 512, 512, 512, 512, 0,0,0, 0, 0, 1.f);
        gnorm_k<<<dim3(G,2), blk, 0, stream>>>(h_c, gnw, gnb, gnms, dflag);
        fbuild_k<<<EC, blk, 0, stream>>>(b0, maxn, h_c, sorted, seg, teg, ea,
                                         eembW, eembB, kb, F_c, bvec, dflag);
        // T = F @ Mp^T
        bgemm_k<ushortT,false,false,false><<<dim3(12, EC/128, 1), blk, 0, stream>>>(
            F_c, MpT, nullptr, T_c, 1536, 1536, 1536, 1536, 0,0,0, 0,0, 1.f);
        // P = softmax(scale * T@F^T + bvec)  -> bf16, fused
        sgemm_sm_k<<<dim3(4, G), blk, 0, stream>>>(
            T_c, F_c, bvec + (long)b0*256, S_c, scale);
        // V'^T_b = Wvo @ F_b^T   (into T_c; T dead after S)
        bgemm_k<ushortT,false,false,false><<<dim3(2, 12, G), blk, 0, stream>>>(
            Wvo, F_c, nullptr, T_c, 1536, 1536, 1536, 256,
            0L, 256L*1536, 256L*1536, 0, 0, 1.f);
        // F_b += P_b @ V'_b + bvo   (A = bf16 P in S_c, lda=512 ushorts)
        bgemm_k<ushortT,true,true,false><<<dim3(12, 2, G), blk, 0, stream>>>(
            (const ushortT*)S_c, T_c, bvo, F_c, 256, 512, 256, 1536,
            131072L, 256L*1536, 256L*1536, 0, 0, 1.f);
        ln_head_k<<<EC, blk, 0, stream>>>(b0, F_c, lng, lnb, headW, headb, gout, dflag);
    }

    final_k<<<128, dim3(128), 0, stream>>>(gout, seg, teg, sorted, ea, (float*)d_out, dflag);
}

// Round 11
// 1143.516 us; speedup vs baseline: 1.0123x; 1.0123x over previous
//
#include <hip/hip_runtime.h>
#include <math.h>

// Problem constants
#define NTOT   8192
#define BGR    128
#define NPER   64
#define EDIR   65536
#define EKEEP  32768
#define EPSC   1e-5f

typedef unsigned short ushortT;
typedef __attribute__((ext_vector_type(8))) short bf16x8;
typedef __attribute__((ext_vector_type(4))) float f32x4;

// Operand dtype codes: 0 = bf16, 1 = f32, 2 = runtime (read *flagp)
#define C_BF 0
#define C_F32 1
#define C_RT 2

// ---------------- dtype helpers ----------------
__device__ __forceinline__ float bf2f(ushortT u) {
    union { unsigned int i; float f; } v; v.i = ((unsigned int)u) << 16; return v.f;
}
__device__ __forceinline__ ushortT f2bf(float f) {
    unsigned int u = __float_as_uint(f);
    u += 0x7FFFu + ((u >> 16) & 1u);   // round to nearest even
    return (ushortT)(u >> 16);
}
__device__ __forceinline__ float get1(const void* p, long i, int f) {
    return f ? ((const float*)p)[i] : bf2f(((const ushortT*)p)[i]);
}
__device__ __forceinline__ float ld1c(const float* p)   { return *p; }
__device__ __forceinline__ float ld1c(const ushortT* p) { return bf2f(*p); }
__device__ __forceinline__ void st1c(float* p, float v)   { *p = v; }
__device__ __forceinline__ void st1c(ushortT* p, float v) { *p = f2bf(v); }
__device__ __forceinline__ int clampi(int v, int lo, int hi) {
    return v < lo ? lo : (v > hi ? hi : v);
}

// direct global->LDS DMA, 16B per lane (lane-linear LDS destination required)
__device__ __forceinline__ void gld16(const void* g, void* l) {
    __builtin_amdgcn_global_load_lds(
        (const __attribute__((address_space(1))) unsigned int*)g,
        (__attribute__((address_space(3))) unsigned int*)l, 16, 0, 0);
}

// Bijective XCD-chunked block-id swizzle (m204).
__device__ __forceinline__ int xcd_swz(int flat, int nwg) {
    const int q = nwg >> 3, r = nwg & 7;
    const int xcd = flat & 7, idx = flat >> 3;
    return (xcd < r ? xcd * (q + 1) : r * (q + 1) + (xcd - r) * q) + idx;
}

// ---------------------------------------------------------------------------
// Float-input dtype detector (validated).
// ---------------------------------------------------------------------------
__launch_bounds__(256)
__global__ void detect_k(const unsigned int* __restrict__ xw, int* __restrict__ flag)
{
    __shared__ int red[256];
    const int t = threadIdx.x;
    int hits = 0;
#pragma unroll
    for (int i = 0; i < 4; ++i) {
        const unsigned w = xw[t*4 + i];
        const unsigned eb = (w >> 7) & 0xFF;
        hits += (eb >= 100 && eb <= 150) ? 1 : 0;
    }
    red[t] = hits; __syncthreads();
#pragma unroll
    for (int s = 128; s > 0; s >>= 1) { if (t < s) red[t] += red[t+s]; __syncthreads(); }
    if (t == 0) *flag = (red[0] < 512) ? 1 : 0;
}

// ---------------------------------------------------------------------------
// Fast bf16 GEMM (validated R7/R9): C = alpha*(A @ B^T) (+bias f32) (+C)
// (relu?). B stored [n][k]. 128x128 tile, 4 waves, 16x16x32 MFMA, BK=64,
// XOR-swizzled global_load_lds staging (SQ_LDS_BANK_CONFLICT==0 measured),
// XCD swizzle. 843 TF measured on the 32768x1536x1536 shapes.
// [R8 NOTE: 256^2 counted-vmcnt variant regressed (709 TF) — wait-ledger
//  mismatch; reverted. Do not re-attempt without the lead-7 derivation.]
// Requires M%128==0, N%128==0, K%64==0, lda/ldb%8==0.
// ---------------------------------------------------------------------------
template<class TC, bool BIAS, bool RESID, bool RELU>
__launch_bounds__(256)
__global__ void bgemm_k(const ushortT* __restrict__ A, const ushortT* __restrict__ B,
                        const float* __restrict__ bias, TC* __restrict__ C,
                        int K, int lda, int ldb, int ldc,
                        long sA, long sB, long sC, long biasOff, long bzStride,
                        float alpha)
{
    const int t = threadIdx.x;
    const int lane = t & 63, wave = t >> 6;
    const int l15 = lane & 15, quad = lane >> 4;
    const int wr = (wave >> 1) * 64, wc = (wave & 1) * 64;

    const int gx = gridDim.x, gy = gridDim.y;
    const int nwg = gx * gy * (int)gridDim.z;
    const int flat = xcd_swz(blockIdx.x + gx * (blockIdx.y + gy * blockIdx.z), nwg);
    const int bx = flat % gx;
    const int by = (flat / gx) % gy;
    const int bz = flat / (gx * gy);

    const int m0 = by * 128, n0 = bx * 128;
    const long z = bz;

    __shared__ __align__(16) ushortT As[128][64];
    __shared__ __align__(16) ushortT Bs[128][64];

    f32x4 acc[4][4] = {};

    const int sr = t >> 3;
    const int ssw = ((t & 7) ^ (sr & 7)) * 8;
    const ushortT* pA = A + z*sA + (long)(m0 + sr) * lda + ssw;
    const ushortT* pB = B + z*sB + (long)(n0 + sr) * ldb + ssw;
    ushortT* lA = &As[sr][(t & 7) * 8];
    ushortT* lB = &Bs[sr][(t & 7) * 8];

    for (int k0 = 0; k0 < K; k0 += 64) {
#pragma unroll
        for (int i = 0; i < 4; ++i) {
            gld16(pA + (long)i*32*lda + k0, lA + i*32*64);
            gld16(pB + (long)i*32*ldb + k0, lB + i*32*64);
        }
        __syncthreads();
#pragma unroll
        for (int kh = 0; kh < 2; ++kh) {
            const int ca = (kh*32 + quad*8) ^ ((l15 & 7) * 8);
            bf16x8 af[4], bfr[4];
#pragma unroll
            for (int i = 0; i < 4; ++i) {
                af[i]  = *(const bf16x8*)&As[wr + i*16 + l15][ca];
                bfr[i] = *(const bf16x8*)&Bs[wc + i*16 + l15][ca];
            }
#pragma unroll
            for (int mt = 0; mt < 4; ++mt)
#pragma unroll
                for (int nt = 0; nt < 4; ++nt)
                    acc[mt][nt] = __builtin_amdgcn_mfma_f32_16x16x32_bf16(af[mt], bfr[nt], acc[mt][nt], 0, 0, 0);
        }
        __syncthreads();
    }

    TC* Cb = C + z * sC;
#pragma unroll
    for (int nt = 0; nt < 4; ++nt) {
        const int col = n0 + wc + nt*16 + l15;
        const float bv = BIAS ? bias[biasOff + z*bzStride + col] : 0.f;
#pragma unroll
        for (int mt = 0; mt < 4; ++mt) {
#pragma unroll
            for (int r = 0; r < 4; ++r) {
                const int row = m0 + wr + mt*16 + quad*4 + r;
                TC* cp = Cb + (long)row * ldc + col;
                float val = alpha * acc[mt][nt][r] + bv;
                if constexpr (RESID) val += ld1c(cp);
                if constexpr (RELU)  val = fmaxf(val, 0.f);
                st1c(cp, val);
            }
        }
    }
}

// ---------------------------------------------------------------------------
// R10: fused S-gemm + row softmax (validated R10 round). Per block: 64 edge
// rows x FULL 256 cols of one batch; writes bf16 P into S_c ushort layout.
// ---------------------------------------------------------------------------
__launch_bounds__(256)
__global__ void sgemm_sm_k(const ushortT* __restrict__ A, const ushortT* __restrict__ B,
                           const float* __restrict__ bvec, float* __restrict__ S,
                           float alpha)
{
    const int t = threadIdx.x;
    const int lane = t & 63, wave = t >> 6;   // wave = column-panel index
    const int l15 = lane & 15, quad = lane >> 4;

    const int gx = gridDim.x;                 // 4 row-blocks of 64
    const int nwg = gx * (int)gridDim.y;
    const int flat = xcd_swz(blockIdx.x + gx * blockIdx.y, nwg);
    const int rb = flat % gx;
    const int z  = flat / gx;

    const int m0 = rb * 64;

    __shared__ __align__(16) ushortT As[64][64];
    __shared__ __align__(16) ushortT Bs[256][64];
    __shared__ float redA[4][64];
    __shared__ float redB[4][64];

    f32x4 acc[4][4] = {};

    const int sr = t >> 3;                    // 0..31 (32 rows per issue)
    const int ssw = ((t & 7) ^ (sr & 7)) * 8;
    const ushortT* pA = A + (long)z*256*1536 + (long)(m0 + sr) * 1536 + ssw;
    const ushortT* pB = B + (long)z*256*1536 + (long)sr * 1536 + ssw;
    ushortT* lA = &As[sr][(t & 7) * 8];
    ushortT* lB = &Bs[sr][(t & 7) * 8];

    for (int k0 = 0; k0 < 1536; k0 += 64) {
        gld16(pA + k0, lA);
        gld16(pA + 32L*1536 + k0, lA + 32*64);
#pragma unroll
        for (int i = 0; i < 8; ++i)
            gld16(pB + (long)i*32*1536 + k0, lB + i*32*64);
        __syncthreads();
#pragma unroll
        for (int kh = 0; kh < 2; ++kh) {
            const int ca = (kh*32 + quad*8) ^ ((l15 & 7) * 8);
            bf16x8 af[4], bfr[4];
#pragma unroll
            for (int i = 0; i < 4; ++i) {
                af[i]  = *(const bf16x8*)&As[i*16 + l15][ca];
                bfr[i] = *(const bf16x8*)&Bs[wave*64 + i*16 + l15][ca];
            }
#pragma unroll
            for (int mt = 0; mt < 4; ++mt)
#pragma unroll
                for (int nt = 0; nt < 4; ++nt)
                    acc[mt][nt] = __builtin_amdgcn_mfma_f32_16x16x32_bf16(af[mt], bfr[nt], acc[mt][nt], 0, 0, 0);
        }
        __syncthreads();
    }

    float bv[4];
#pragma unroll
    for (int nt = 0; nt < 4; ++nt)
        bv[nt] = bvec[z*256 + wave*64 + nt*16 + l15];

    // pass 1: per-row max (64 cols in-wave, then cross-wave via LDS)
#pragma unroll
    for (int mt = 0; mt < 4; ++mt) {
#pragma unroll
        for (int r = 0; r < 4; ++r) {
            float m = -3.4e38f;
#pragma unroll
            for (int nt = 0; nt < 4; ++nt)
                m = fmaxf(m, alpha * acc[mt][nt][r] + bv[nt]);
#pragma unroll
            for (int sh = 1; sh < 16; sh <<= 1)
                m = fmaxf(m, __shfl_xor(m, sh));
            if (l15 == 0) redA[wave][mt*16 + quad*4 + r] = m;
        }
    }
    __syncthreads();
    // pass 2: exp + row sum (exp overwrites acc)
#pragma unroll
    for (int mt = 0; mt < 4; ++mt) {
#pragma unroll
        for (int r = 0; r < 4; ++r) {
            const int lr = mt*16 + quad*4 + r;
            const float mx = fmaxf(fmaxf(redA[0][lr], redA[1][lr]),
                                   fmaxf(redA[2][lr], redA[3][lr]));
            float s = 0.f;
#pragma unroll
            for (int nt = 0; nt < 4; ++nt) {
                const float e = __expf(alpha * acc[mt][nt][r] + bv[nt] - mx);
                acc[mt][nt][r] = e;
                s += e;
            }
#pragma unroll
            for (int sh = 1; sh < 16; sh <<= 1)
                s += __shfl_xor(s, sh);
            if (l15 == 0) redB[wave][lr] = s;
        }
    }
    __syncthreads();
    // pass 3: normalize + write bf16 P (row*512 ushorts, batch stride 131072)
    ushortT* P = (ushortT*)S + (long)z*131072 + (long)m0*512;
#pragma unroll
    for (int mt = 0; mt < 4; ++mt) {
#pragma unroll
        for (int r = 0; r < 4; ++r) {
            const int lr = mt*16 + quad*4 + r;
            const float den = redB[0][lr] + redB[1][lr] + redB[2][lr] + redB[3][lr];
            const float inv = 1.f / den;
#pragma unroll
            for (int nt = 0; nt < 4; ++nt)
                P[(long)lr*512 + wave*64 + nt*16 + l15] = f2bf(acc[mt][nt][r] * inv);
        }
    }
}

// ---------------- block reduction (256 threads) ----------------
__device__ __forceinline__ float blockReduceSum(float v, float* red, int t)
{
    red[t] = v; __syncthreads();
#pragma unroll
    for (int s = 128; s > 0; s >>= 1) {
        if (t < s) red[t] += red[t + s];
        __syncthreads();
    }
    const float r = red[0];
    __syncthreads();
    return r;
}

// ---------------------------------------------------------------------------
// Weight convert / transpose-convert to bf16 fast-path layouts.
// ---------------------------------------------------------------------------
__launch_bounds__(256)
__global__ void convbf_k(const void* __restrict__ in, ushortT* __restrict__ out,
                         long n4, const int* __restrict__ flagp)
{
    const int f = *flagp;
    const long i = (long)blockIdx.x*256 + threadIdx.x;
    if (i >= n4) return;
    const long i0 = i * 4;
    if (f) {
        const float4 v = *(const float4*)((const float*)in + i0);
        ushort4 o; o.x=f2bf(v.x); o.y=f2bf(v.y); o.z=f2bf(v.z); o.w=f2bf(v.w);
        *(ushort4*)(out + i0) = o;
    } else {
        *(ushort4*)(out + i0) = *(const ushort4*)((const ushortT*)in + i0);
    }
}

// R10: 4-way batched 1536x1536 transpose-convert (z selects src/dst pair)
__launch_bounds__(256)
__global__ void tconvbf4_k(const void* __restrict__ i0, const void* __restrict__ i1,
                           const void* __restrict__ i2, const void* __restrict__ i3,
                           ushortT* __restrict__ o0, ushortT* __restrict__ o1,
                           ushortT* __restrict__ o2, ushortT* __restrict__ o3,
                           const int* __restrict__ flagp)
{
    const int f = *flagp;
    const void* in; ushortT* out;
    switch (blockIdx.z) {
        case 0:  in = i0; out = o0; break;
        case 1:  in = i1; out = o1; break;
        case 2:  in = i2; out = o2; break;
        default: in = i3; out = o3; break;
    }
    __shared__ float tile[32][33];
    const int bx = blockIdx.x, by = blockIdx.y;
    const int tx = threadIdx.x & 31, ty = threadIdx.x >> 5;
#pragma unroll
    for (int i = 0; i < 4; ++i) {
        const int k = by*32 + ty + i*8;
        tile[ty + i*8][tx] = get1(in, (long)k*1536 + bx*32 + tx, f);
    }
    __syncthreads();
#pragma unroll
    for (int i = 0; i < 4; ++i) {
        const int n = bx*32 + ty + i*8;
        out[(long)n*1536 + by*32 + tx] = f2bf(tile[tx][ty + i*8]);
    }
}

// R9: transpose-convert [256][512] k-major weight into Wg2T[n][512] at column
// offset koff (fused-gconv2 B operand).
__launch_bounds__(256)
__global__ void tconv512_k(const void* __restrict__ in, ushortT* __restrict__ out,
                           int koff, const int* __restrict__ flagp)
{
    const int f = *flagp;
    __shared__ float tile[32][33];
    const int bx = blockIdx.x, by = blockIdx.y;
    const int tx = threadIdx.x & 31, ty = threadIdx.x >> 5;
#pragma unroll
    for (int i = 0; i < 4; ++i) {
        const int k = by*32 + ty + i*8;
        tile[ty + i*8][tx] = get1(in, (long)k*512 + bx*32 + tx, f);
    }
    __syncthreads();
#pragma unroll
    for (int i = 0; i < 4; ++i) {
        const int n = bx*32 + ty + i*8;
        out[(long)n*512 + koff + by*32 + tx] = f2bf(tile[tx][ty + i*8]);
    }
}

__launch_bounds__(256)
__global__ void convf32_k(const void* __restrict__ in, float* __restrict__ out,
                          int n, const int* __restrict__ flagp)
{
    const int f = *flagp;
    const int i = blockIdx.x*256 + threadIdx.x;
    if (i < n) out[i] = get1(in, i, f);
}

// ---------------------------------------------------------------------------
// colcomb split (validated): partials + deterministic reduce.
// ---------------------------------------------------------------------------
__launch_bounds__(256)
__global__ void colcomb_part_k(const void* __restrict__ v, int cv, long voff,
                               const void* __restrict__ W, int cW,
                               float* __restrict__ part, const int* __restrict__ flagp)
{
    const int rtf = *flagp;
    const int fv = (cv == C_RT) ? rtf : cv;
    const int fW = (cW == C_RT) ? rtf : cW;
    const int d = blockIdx.x*256 + threadIdx.x;
    const int c0 = blockIdx.y * 24;
    float a = 0.f;
#pragma unroll
    for (int i = 0; i < 24; ++i) {
        const int c = c0 + i;
        a += get1(v, voff + c, fv) * get1(W, (long)c*1536 + d, fW);
    }
    part[blockIdx.y * 1536 + d] = a;
}

__launch_bounds__(256)
__global__ void colcomb_red_k(const float* __restrict__ part,
                              const void* __restrict__ b, int cb,
                              float* __restrict__ out, const int* __restrict__ flagp)
{
    const int rtf = *flagp;
    const int fb = (cb == C_RT) ? rtf : cb;
    const int d = blockIdx.x*256 + threadIdx.x;
    float a = get1(b, d, fb);
#pragma unroll 8
    for (int cy = 0; cy < 64; ++cy) a += part[cy*1536 + d];
    out[d] = a;
}

// ---------------------------------------------------------------------------
// rowdot: out[r] = scale * sum_c bf2f(W[r*1536+c]) * v[c]
// ---------------------------------------------------------------------------
__launch_bounds__(256)
__global__ void rowdot_k(const ushortT* __restrict__ W, const float* __restrict__ v,
                         float* __restrict__ out, float scale)
{
    const int r = blockIdx.x, t = threadIdx.x;
    __shared__ float red[256];
    float p = 0.f;
    for (int c = t; c < 1536; c += 256) p += bf2f(W[(long)r*1536 + c]) * v[c];
    const float tot = blockReduceSum(p, red, t);
    if (t == 0) out[r] = scale * tot;
}

// ---------------------------------------------------------------------------
// gconv1 fused (validated; R10 node-split across blockIdx.y)
// ---------------------------------------------------------------------------
__launch_bounds__(256)
__global__ void gconv1_k(int b0, const void* __restrict__ x, const int* __restrict__ edges,
                         const void* __restrict__ ea,
                         const void* __restrict__ wembW, const void* __restrict__ wembB,
                         const void* __restrict__ Wrel, const void* __restrict__ brel,
                         const void* __restrict__ Wroot, ushortT* __restrict__ ah,
                         const int* __restrict__ flagp)
{
    const int f = *flagp;
    const int bl = blockIdx.x, g = b0 + bl, t = threadIdx.x;
    const int nb0 = blockIdx.y * 32;
    __shared__ float s_x[64][5];
    __shared__ float s_agg[64][5];
    __shared__ int   s_cnt[64];
    __shared__ int   s_off[65];
    __shared__ int   s_src[512];
    __shared__ float s_w[512];

    if (t < 64) s_cnt[t] = 0;
    if (t < 320) s_x[t/5][t%5] = get1(x, (long)(g*64 + t/5)*5 + (t%5), f);
    __syncthreads();

    const float w0 = get1(wembW,0,f), w1 = get1(wembW,1,f), w2 = get1(wembW,2,f);
    const float wb = get1(wembB,0,f);
    int sl[2], dl[2], slot[2]; float wv[2];
#pragma unroll
    for (int e2 = 0; e2 < 2; ++e2) {
        const int e = g*512 + t + 256*e2;
        const int s = edges[e], d = edges[EDIR + e];
        sl[e2] = clampi(s - g*64, 0, 63); dl[e2] = clampi(d - g*64, 0, 63);
        const float a0 = get1(ea, 2L*e, f), a1 = get1(ea, 2L*e+1, f);
        wv[e2] = fmaxf(a0*w0 + ((a1 < 0.5f) ? w1 : w2) + wb, 0.f);
        slot[e2] = atomicAdd(&s_cnt[dl[e2]], 1);
    }
    __syncthreads();
    if (t == 0) {
        int r = 0;
        for (int i = 0; i < 64; ++i) { s_off[i] = r; r += s_cnt[i]; }
        s_off[64] = r;
    }
    __syncthreads();
#pragma unroll
    for (int e2 = 0; e2 < 2; ++e2) {
        const int p = s_off[dl[e2]] + slot[e2];
        s_src[p] = sl[e2]; s_w[p] = wv[e2];
    }
    __syncthreads();
    if (t < 160) {
        const int n = nb0 + t/5, k = t%5;
        float acc = 0.f;
        for (int i = s_off[n]; i < s_off[n+1]; ++i) acc += s_w[i] * s_x[s_src[i]][k];
        s_agg[n][k] = acc;
    }
    __syncthreads();
    float wr[5], wo[5];
#pragma unroll
    for (int k = 0; k < 5; ++k) { wr[k] = get1(Wrel, k*256 + t, f); wo[k] = get1(Wroot, k*256 + t, f); }
    const float bb = get1(brel, t, f);
    for (int n = nb0; n < nb0 + 32; ++n) {
        float v = bb;
#pragma unroll
        for (int k = 0; k < 5; ++k) v += s_agg[n][k]*wr[k] + s_x[n][k]*wo[k];
        ah[(long)(bl*64 + n)*512 + 256 + t] = f2bf(fmaxf(v, 0.f));
    }
}

// ---------------------------------------------------------------------------
// gconv2 aggregation (validated; R10 node-split across blockIdx.y)
// ---------------------------------------------------------------------------
__launch_bounds__(256)
__global__ void gconv2_agg_k(int b0, ushortT* __restrict__ ah, const int* __restrict__ edges,
                             const void* __restrict__ ea,
                             const void* __restrict__ wembW, const void* __restrict__ wembB,
                             const int* __restrict__ flagp)
{
    const int f = *flagp;
    const int bl = blockIdx.x, g = b0 + bl, t = threadIdx.x;
    const int nb0 = blockIdx.y * 32;
    __shared__ int   s_cnt[64];
    __shared__ int   s_off[65];
    __shared__ int   s_src[512];
    __shared__ float s_w[512];

    if (t < 64) s_cnt[t] = 0;
    __syncthreads();

    const float w0 = get1(wembW,0,f), w1 = get1(wembW,1,f), w2 = get1(wembW,2,f);
    const float wb = get1(wembB,0,f);
    int sl[2], dl[2], slot[2]; float wv[2];
#pragma unroll
    for (int e2 = 0; e2 < 2; ++e2) {
        const int e = g*512 + t + 256*e2;
        const int s = edges[e], d = edges[EDIR + e];
        sl[e2] = clampi(s - g*64, 0, 63); dl[e2] = clampi(d - g*64, 0, 63);
        const float a0 = get1(ea, 2L*e, f), a1 = get1(ea, 2L*e+1, f);
        wv[e2] = fmaxf(a0*w0 + ((a1 < 0.5f) ? w1 : w2) + wb, 0.f);
        slot[e2] = atomicAdd(&s_cnt[dl[e2]], 1);
    }
    __syncthreads();
    if (t == 0) {
        int r = 0;
        for (int i = 0; i < 64; ++i) { s_off[i] = r; r += s_cnt[i]; }
        s_off[64] = r;
    }
    __syncthreads();
#pragma unroll
    for (int e2 = 0; e2 < 2; ++e2) {
        const int p = s_off[dl[e2]] + slot[e2];
        s_src[p] = sl[e2]; s_w[p] = wv[e2];
    }
    __syncthreads();
    for (int n = nb0; n < nb0 + 32; ++n) {
        float acc = 0.f;
        const int i0 = s_off[n], i1 = s_off[n+1];
        for (int i = i0; i < i1; ++i)
            acc += s_w[i] * bf2f(ah[(long)(bl*64 + s_src[i])*512 + 256 + t]);
        ah[(long)(bl*64 + n)*512 + t] = f2bf(acc);
    }
}

// ---------------------------------------------------------------------------
// GraphNorm (validated; split across blockIdx.y)
// ---------------------------------------------------------------------------
__launch_bounds__(256)
__global__ void gnorm_k(ushortT* __restrict__ h, const void* __restrict__ gw,
                        const void* __restrict__ gb, const void* __restrict__ gms,
                        const int* __restrict__ flagp)
{
    const int f0 = *flagp;
    const int bl = blockIdx.x, t = threadIdx.x;
    const int f = t + 256*blockIdx.y;
    float acc = 0.f;
    for (int n = 0; n < 64; ++n) acc += bf2f(h[(bl*64+n)*512 + f]);
    const float m2 = get1(gms, f, f0) * (acc * (1.f/64.f));
    float v = 0.f;
    for (int n = 0; n < 64; ++n) { const float d = bf2f(h[(bl*64+n)*512 + f]) - m2; v += d*d; }
    const float rs = rsqrtf(v*(1.f/64.f) + EPSC);
    const float g = get1(gw, f, f0), bb = get1(gb, f, f0);
    for (int n = 0; n < 64; ++n) {
        const int idx = (bl*64+n)*512 + f;
        h[idx] = f2bf(g * (bf2f(h[idx]) - m2) * rs + bb);
    }
}

// ---------------------------------------------------------------------------
// SplitSyndromes sort (unchanged — validated)
// ---------------------------------------------------------------------------
__launch_bounds__(256)
__global__ void sort_k(const int* __restrict__ edges, int* __restrict__ sorted_orig,
                       int* __restrict__ se, int* __restrict__ te)
{
    const int b = blockIdx.x, t = threadIdx.x;
    __shared__ int s_keep[512];
    __shared__ int s_key[512];
    __shared__ int s_ckey[256];
    __shared__ int s_corig[256];
#pragma unroll
    for (int e2 = 0; e2 < 2; ++e2) {
        const int el = t + 256*e2;
        const int e = b*512 + el;
        const int s = edges[e], d = edges[EDIR + e];
        s_keep[el] = (s > d) ? 1 : 0;
        s_key[el]  = ((s - b*64) << 6) | (d - b*64);
    }
    __syncthreads();
#pragma unroll
    for (int e2 = 0; e2 < 2; ++e2) {
        const int el = t + 256*e2;
        if (s_keep[el]) {
            int pos = 0;
            for (int j = 0; j < el; ++j) pos += s_keep[j];
            s_ckey[pos]  = s_key[el];
            s_corig[pos] = b*512 + el;
        }
    }
    __syncthreads();
    const int ki = s_ckey[t];
    int rank = 0;
    for (int j = 0; j < 256; ++j) {
        const int kj = s_ckey[j];
        rank += (kj < ki || (kj == ki && j < t)) ? 1 : 0;
    }
    const int orig = s_corig[t];
    const int p = b*256 + rank;
    sorted_orig[p] = orig;
    se[p] = edges[orig];
    te[p] = edges[EDIR + orig];
}

// ---------------------------------------------------------------------------
// Build F_c + bvec[ge] = F[e] . kb  (unchanged — validated)
// ---------------------------------------------------------------------------
__launch_bounds__(256)
__global__ void fbuild_k(int b0, int maxn, const ushortT* __restrict__ h,
                         const int* __restrict__ sorted_orig,
                         const int* __restrict__ se, const int* __restrict__ te,
                         const void* __restrict__ ea,
                         const void* __restrict__ eW, const void* __restrict__ eB,
                         const float* __restrict__ kb,
                         ushortT* __restrict__ F, float* __restrict__ bvec,
                         const int* __restrict__ flagp)
{
    const int fl = *flagp;
    const int e = blockIdx.x, t = threadIdx.x;
    __shared__ float red[256];
    const int ge = b0*256 + e;
    const int s = clampi(se[ge] - b0*64, 0, maxn);
    const int d = clampi(te[ge] - b0*64, 0, maxn);
    const int orig = clampi(sorted_orig[ge], 0, EDIR-1);
    const float a0 = get1(ea, 2L*orig, fl), a1 = get1(ea, 2L*orig + 1, fl);
    float partial = 0.f;
#pragma unroll
    for (int c = 0; c < 6; ++c) {
        const int col = c*256 + t;
        float v;
        if (c < 2) {
            v = bf2f(h[(long)s*512 + col]);
        } else if (c < 4) {
            const int ff = col - 512;
            v = fmaxf(a0*get1(eW, ff, fl)
                      + ((a1 < 0.5f) ? get1(eW, 512+ff, fl) : get1(eW, 1024+ff, fl))
                      + get1(eB, ff, fl), 0.f);
        } else {
            v = bf2f(h[(long)d*512 + (col - 1024)]);
        }
        F[(long)e*1536 + col] = f2bf(v);
        partial += v * kb[col];
    }
    const float tot = blockReduceSum(partial, red, t);
    if (t == 0) bvec[ge] = tot;
}

// ---------------------------------------------------------------------------
// R11: fused LayerNorm + head dot, ONE WAVE PER EDGE, zero barriers/LDS.
// R10's block-reduce version (3 x blockReduceSum = ~27 __syncthreads over
// 3 KB) measured 280 us with VALUBusy 7% — pure barrier-stall. Per-wave:
// 24 elems/lane (3 x bf16x8 coalesced), three 6-round __shfl_xor butterflies
// (sum -> mu; centered sumsq -> rs; weighted dot -> out). 4 edges per block.
// ---------------------------------------------------------------------------
__launch_bounds__(256)
__global__ void ln_head_k(int b0, const ushortT* __restrict__ F, const void* __restrict__ lng,
                          const void* __restrict__ lnb, const void* __restrict__ hW,
                          const void* __restrict__ hB, float* __restrict__ gout,
                          const int* __restrict__ flagp)
{
    const int fl = *flagp;
    const int t = threadIdx.x;
    const int lane = t & 63, w = t >> 6;
    const long e = (long)blockIdx.x * 4 + w;
    const ushortT* Fr = F + e * 1536;

    float xv[24];
    float s = 0.f;
#pragma unroll
    for (int j = 0; j < 3; ++j) {
        const bf16x8 v = *(const bf16x8*)&Fr[j*512 + lane*8];
#pragma unroll
        for (int jj = 0; jj < 8; ++jj) {
            xv[j*8 + jj] = bf2f((ushortT)v[jj]);
            s += xv[j*8 + jj];
        }
    }
#pragma unroll
    for (int sh = 1; sh < 64; sh <<= 1) s += __shfl_xor(s, sh);
    const float mu = s * (1.f/1536.f);

    float ss = 0.f;
#pragma unroll
    for (int i = 0; i < 24; ++i) { const float d = xv[i] - mu; ss += d*d; }
#pragma unroll
    for (int sh = 1; sh < 64; sh <<= 1) ss += __shfl_xor(ss, sh);
    const float rs = rsqrtf(ss * (1.f/1536.f) + EPSC);

    float p = 0.f;
#pragma unroll
    for (int j = 0; j < 3; ++j) {
#pragma unroll
        for (int jj = 0; jj < 8; ++jj) {
            const int col = j*512 + lane*8 + jj;
            p += (get1(lng, col, fl) * (xv[j*8 + jj] - mu) * rs + get1(lnb, col, fl))
                 * get1(hW, col, fl);
        }
    }
#pragma unroll
    for (int sh = 1; sh < 64; sh <<= 1) p += __shfl_xor(p, sh);
    if (lane == 0) gout[b0*256 + e] = p + get1(hB, 0, fl);
}

// ---------------- final output assembly (unchanged — validated) -------------
__launch_bounds__(128)
__global__ void final_k(const float* __restrict__ gout, const int* __restrict__ se,
                        const int* __restrict__ te, const int* __restrict__ sorted_orig,
                        const void* __restrict__ ea, float* __restrict__ out,
                        const int* __restrict__ flagp)
{
    const int fl = *flagp;
    const int b = blockIdx.x, j = threadIdx.x;
    const int e0 = b*256 + 2*j, e1 = e0 + 1;
    const float p0 = gout[e0], p1 = gout[e1];
    const int idx = (p1 < p0) ? 1 : 0;
    const float val = idx ? p1 : p0;
    const int eo = idx ? e1 : e0;
    const int orig = clampi(sorted_orig[eo], 0, EDIR-1);
    const float cls = get1(ea, 2L*orig + 1, fl);
    out[(b*128 + j)*2 + 0] = (float)se[e0];
    out[(b*128 + j)*2 + 1] = (float)te[e0];
    out[32768 + b*128 + j] = val;
    out[32768 + 16384 + b*128 + j] = cls;
}

// ---------------------------------------------------------------------------
// Launch. R11: per-wave barrier-free ln_head (280 -> ~30 us predicted);
// everything else identical to R10.
// ---------------------------------------------------------------------------
extern "C" void kernel_launch(void* const* d_in, const int* in_sizes, int n_in,
                              void* d_out, int out_size, void* d_ws, size_t ws_size,
                              hipStream_t stream)
{
    (void)out_size;

    const void* x     = d_in[0];
    const int*  edges = (const int*)d_in[1];
    const void* ea    = d_in[2];

    int ws0 = 3;
    while (ws0 < n_in && in_sizes[ws0] != 3) ++ws0;
    if (ws0 + 27 > n_in) ws0 = 5;

    const void* wembW  = d_in[ws0 + 0];
    const void* wembB  = d_in[ws0 + 1];
    const void* g1Wrel = d_in[ws0 + 2];
    const void* g1brel = d_in[ws0 + 3];
    const void* g1Wroot= d_in[ws0 + 4];
    const void* g2Wrel = d_in[ws0 + 5];
    const void* g2brel = d_in[ws0 + 6];
    const void* g2Wroot= d_in[ws0 + 7];
    const void* gnw    = d_in[ws0 + 8];
    const void* gnb    = d_in[ws0 + 9];
    const void* gnms   = d_in[ws0 + 10];
    const void* eembW  = d_in[ws0 + 11];
    const void* eembB  = d_in[ws0 + 12];
    const void* qkvW   = d_in[ws0 + 13];
    const void* qkvb   = d_in[ws0 + 14];
    const void* inWq   = d_in[ws0 + 15];
    const void* inWk   = d_in[ws0 + 16];
    const void* inWv   = d_in[ws0 + 17];
    const void* inbq   = d_in[ws0 + 18];
    // inbk (ws0+19): row-constant score terms -> drop in softmax
    const void* inbv   = d_in[ws0 + 20];
    const void* outW   = d_in[ws0 + 21];
    const void* outb   = d_in[ws0 + 22];
    const void* lng    = d_in[ws0 + 23];
    const void* lnb    = d_in[ws0 + 24];
    const void* headW  = d_in[ws0 + 25];
    const void* headb  = d_in[ws0 + 26];

    char* ws = (char*)d_ws;
    size_t off = 0;
    auto alloc = [&](size_t bytes) {
        void* p = ws + off;
        off = (off + bytes + 255) & ~(size_t)255;
        return p;
    };
    // ---- fixed region (~12 MB) ----
    int*     dflag  = (int*)    alloc(256);
    float*   gout   = (float*)  alloc(EKEEP*4);
    int*     sorted = (int*)    alloc(EKEEP*4);
    int*     seg    = (int*)    alloc(EKEEP*4);
    int*     teg    = (int*)    alloc(EKEEP*4);
    float*   bvec   = (float*)  alloc(EKEEP*4);
    float*   bqc    = (float*)  alloc(1536*4);
    float*   bvc    = (float*)  alloc(1536*4);
    float*   kb     = (float*)  alloc(1536*4);
    float*   bvo    = (float*)  alloc(1536*4);
    float*   g2bf   = (float*)  alloc(512*4);
    float*   colpart= (float*)  alloc(64L*1536*4);
    ushortT* Wg2T   = (ushortT*)alloc(512L*512*2);     // fused gconv2 B, [n][k]
    ushortT* MpWv   = (ushortT*)alloc(2L*1536*1536*2); // [Mp^T ; Wvo] contiguous
    ushortT* MpT    = MpWv;                            // Mp^T, [n][k]
    ushortT* Wvo    = MpWv + 1536L*1536;               // Wvo, ROW-major [m][k]
    const size_t fixedB = off;

    // ---- union region (phase-W scratch; overlaps chunk scratch) ----
    const long W2 = 1536L * 1536;
    ushortT* Wqc    = (ushortT*)(ws + fixedB);
    ushortT* Wkc    = Wqc + W2;
    ushortT* Wvc    = Wqc + 2*W2;
    ushortT* outWT  = Wqc + 3*W2;
    ushortT* qkvWbf = Wqc + 4*W2;     // 1536x4608
    ushortT* inWqT  = Wqc + 7*W2;
    ushortT* inWkT  = Wqc + 8*W2;     // adjacent (z=3 B stride = W2)
    ushortT* inWvT  = Wqc + 9*W2;

    // ---- chunk scratch (G=128 guaranteed: perG = 1.97 MB -> ~252 MB) ----
    const size_t perG = 64L*512*2 + 64L*512*2 + 2L*256*1536*2 + 256L*256*4;
    int G = 128;
    while (G > 2 && fixedB + (size_t)G*perG + 65536 > ws_size) G >>= 1;

    size_t coff = fixedB;
    auto calloc2 = [&](size_t bytes) {
        void* p = ws + coff;
        coff = (coff + bytes + 255) & ~(size_t)255;
        return p;
    };
    ushortT* h_c  = (ushortT*)calloc2((size_t)G*64*512*2);
    ushortT* ah_c = (ushortT*)calloc2((size_t)G*64*512*2);   // [ag | h1] K=512
    ushortT* F_c  = (ushortT*)calloc2((size_t)G*256*1536*2);
    ushortT* T_c  = (ushortT*)calloc2((size_t)G*256*1536*2); // T, then V'^T
    float*   S_c  = (float*)  calloc2((size_t)G*256*256*4);  // bf16 P lives here

    const float scale = 0.02551551815399144f;  // 1/sqrt(1536)
    const dim3 blk(256);

    detect_k<<<1, blk, 0, stream>>>((const unsigned int*)x, dflag);
    sort_k<<<128, blk, 0, stream>>>(edges, sorted, seg, teg);

    // ---- phase W ----
    convbf_k<<<(1536*4608/4 + 255)/256, blk, 0, stream>>>(qkvW, qkvWbf, 1536L*4608/4, dflag);
    tconvbf4_k<<<dim3(48,48,4), blk, 0, stream>>>(inWq, inWk, inWv, outW,
                                                  inWqT, inWkT, inWvT, outWT, dflag);
    tconv512_k<<<dim3(16,8), blk, 0, stream>>>(g2Wrel, Wg2T, 0, dflag);
    tconv512_k<<<dim3(16,8), blk, 0, stream>>>(g2Wroot, Wg2T, 256, dflag);
    convf32_k<<<2, blk, 0, stream>>>(g2brel, g2bf, 512, dflag);
    // (Wqc,Wkc,Wvc) z=3 batch: A = qkvWbf k-slices (sA=1536), B = inW{q,k,v}T
    bgemm_k<ushortT,false,false,false><<<dim3(12,12,3), blk, 0, stream>>>(
        qkvWbf, inWqT, nullptr, Wqc, 1536, 4608, 1536, 1536,
        1536L, W2, W2, 0, 0, 1.f);
    colcomb_part_k<<<dim3(6,64), blk, 0, stream>>>(qkvb, C_RT, 0, inWq, C_RT, colpart, dflag);
    colcomb_red_k<<<6, blk, 0, stream>>>(colpart, inbq, C_RT, bqc, dflag);
    // kb = scale * Wkc @ bqc
    rowdot_k<<<1536, blk, 0, stream>>>(Wkc, bqc, kb, scale);
    colcomb_part_k<<<dim3(6,64), blk, 0, stream>>>(qkvb, C_RT, 3072, inWv, C_RT, colpart, dflag);
    colcomb_red_k<<<6, blk, 0, stream>>>(colpart, inbv, C_RT, bvc, dflag);
    // (MpT, Wvo) z=2 batch, unscaled (scale lives in the S-gemm alpha):
    //   z=0: MpT = Wkc @ Wqc^T
    //   z=1: Wvo = Wvc @ outWT^T = Wvc @ outW   (row-major Wvo)
    bgemm_k<ushortT,false,false,false><<<dim3(12,12,2), blk, 0, stream>>>(
        Wkc, Wqc, nullptr, MpT, 1536, 1536, 1536, 1536,
        W2, 3*W2, W2, 0, 0, 1.f);
    colcomb_part_k<<<dim3(6,64), blk, 0, stream>>>(bvc, C_F32, 0, outW, C_RT, colpart, dflag);
    colcomb_red_k<<<6, blk, 0, stream>>>(colpart, outb, C_RT, bvo, dflag);

    // ---- per-chunk pipeline ----
    const int nchunk = 128 / G;
    const int EC = G * 256;
    for (int c = 0; c < nchunk; ++c) {
        const int b0 = c * G;
        const int maxn = G*64 - 1;
        gconv1_k<<<dim3(G,2), blk, 0, stream>>>(b0, x, edges, ea, wembW, wembB,
                                                g1Wrel, g1brel, g1Wroot, ah_c, dflag);
        gconv2_agg_k<<<dim3(G,2), blk, 0, stream>>>(b0, ah_c, edges, ea, wembW, wembB, dflag);
        // h = relu([ag|h1] @ Wg2T^T + g2b)   (fused gconv2, K=512)
        bgemm_k<ushortT,true,false,true><<<dim3(4, G/2, 1), blk, 0, stream>>>(
            ah_c, Wg2T, g2bf, h_c, 512, 512, 512, 512, 0,0,0, 0, 0, 1.f);
        gnorm_k<<<dim3(G,2), blk, 0, stream>>>(h_c, gnw, gnb, gnms, dflag);
        fbuild_k<<<EC, blk, 0, stream>>>(b0, maxn, h_c, sorted, seg, teg, ea,
                                         eembW, eembB, kb, F_c, bvec, dflag);
        // T = F @ Mp^T
        bgemm_k<ushortT,false,false,false><<<dim3(12, EC/128, 1), blk, 0, stream>>>(
            F_c, MpT, nullptr, T_c, 1536, 1536, 1536, 1536, 0,0,0, 0,0, 1.f);
        // P = softmax(scale * T@F^T + bvec)  -> bf16, fused
        sgemm_sm_k<<<dim3(4, G), blk, 0, stream>>>(
            T_c, F_c, bvec + (long)b0*256, S_c, scale);
        // V'^T_b = Wvo @ F_b^T   (into T_c; T dead after S)
        bgemm_k<ushortT,false,false,false><<<dim3(2, 12, G), blk, 0, stream>>>(
            Wvo, F_c, nullptr, T_c, 1536, 1536, 1536, 256,
            0L, 256L*1536, 256L*1536, 0, 0, 1.f);
        // F_b += P_b @ V'_b + bvo   (A = bf16 P in S_c, lda=512 ushorts)
        bgemm_k<ushortT,true,true,false><<<dim3(12, 2, G), blk, 0, stream>>>(
            (const ushortT*)S_c, T_c, bvo, F_c, 256, 512, 256, 1536,
            131072L, 256L*1536, 256L*1536, 0, 0, 1.f);
        ln_head_k<<<EC/4, blk, 0, stream>>>(b0, F_c, lng, lnb, headW, headb, gout, dflag);
    }

    final_k<<<128, dim3(128), 0, stream>>>(gout, seg, teg, sorted, ea, (float*)d_out, dflag);
}

// Round 12
// 924.605 us; speedup vs baseline: 1.2520x; 1.2368x over previous
//
#include <hip/hip_runtime.h>
#include <math.h>

// Problem constants
#define NTOT   8192
#define BGR    128
#define NPER   64
#define EDIR   65536
#define EKEEP  32768
#define EPSC   1e-5f

typedef unsigned short ushortT;
typedef __attribute__((ext_vector_type(8))) short bf16x8;
typedef __attribute__((ext_vector_type(4))) float f32x4;

// Operand dtype codes: 0 = bf16, 1 = f32, 2 = runtime (read *flagp)
#define C_BF 0
#define C_F32 1
#define C_RT 2

// ---------------- dtype helpers ----------------
__device__ __forceinline__ float bf2f(ushortT u) {
    union { unsigned int i; float f; } v; v.i = ((unsigned int)u) << 16; return v.f;
}
__device__ __forceinline__ ushortT f2bf(float f) {
    unsigned int u = __float_as_uint(f);
    u += 0x7FFFu + ((u >> 16) & 1u);   // round to nearest even
    return (ushortT)(u >> 16);
}
__device__ __forceinline__ float get1(const void* p, long i, int f) {
    return f ? ((const float*)p)[i] : bf2f(((const ushortT*)p)[i]);
}
__device__ __forceinline__ float ld1c(const float* p)   { return *p; }
__device__ __forceinline__ float ld1c(const ushortT* p) { return bf2f(*p); }
__device__ __forceinline__ void st1c(float* p, float v)   { *p = v; }
__device__ __forceinline__ void st1c(ushortT* p, float v) { *p = f2bf(v); }
__device__ __forceinline__ int clampi(int v, int lo, int hi) {
    return v < lo ? lo : (v > hi ? hi : v);
}

// direct global->LDS DMA, 16B per lane (lane-linear LDS destination required)
__device__ __forceinline__ void gld16(const void* g, void* l) {
    __builtin_amdgcn_global_load_lds(
        (const __attribute__((address_space(1))) unsigned int*)g,
        (__attribute__((address_space(3))) unsigned int*)l, 16, 0, 0);
}

// Bijective XCD-chunked block-id swizzle (m204).
__device__ __forceinline__ int xcd_swz(int flat, int nwg) {
    const int q = nwg >> 3, r = nwg & 7;
    const int xcd = flat & 7, idx = flat >> 3;
    return (xcd < r ? xcd * (q + 1) : r * (q + 1) + (xcd - r) * q) + idx;
}

// ---------------------------------------------------------------------------
// Float-input dtype detector (validated).
// ---------------------------------------------------------------------------
__launch_bounds__(256)
__global__ void detect_k(const unsigned int* __restrict__ xw, int* __restrict__ flag)
{
    __shared__ int red[256];
    const int t = threadIdx.x;
    int hits = 0;
#pragma unroll
    for (int i = 0; i < 4; ++i) {
        const unsigned w = xw[t*4 + i];
        const unsigned eb = (w >> 7) & 0xFF;
        hits += (eb >= 100 && eb <= 150) ? 1 : 0;
    }
    red[t] = hits; __syncthreads();
#pragma unroll
    for (int s = 128; s > 0; s >>= 1) { if (t < s) red[t] += red[t+s]; __syncthreads(); }
    if (t == 0) *flag = (red[0] < 512) ? 1 : 0;
}

// ---------------------------------------------------------------------------
// Fast bf16 GEMM (validated R7/R9): C = alpha*(A @ B^T) (+bias f32) (+C)
// (relu?). B stored [n][k]. 128x128 tile, 4 waves, 16x16x32 MFMA, BK=64,
// XOR-swizzled global_load_lds staging (SQ_LDS_BANK_CONFLICT==0 measured),
// XCD swizzle. 843 TF measured on the 32768x1536x1536 shapes.
// [R8 NOTE: 256^2 counted-vmcnt variant regressed (709 TF) — wait-ledger
//  mismatch; reverted. Do not re-attempt without the lead-7 derivation.]
// Requires M%128==0, N%128==0, K%64==0, lda/ldb%8==0.
// ---------------------------------------------------------------------------
template<class TC, bool BIAS, bool RESID, bool RELU>
__launch_bounds__(256)
__global__ void bgemm_k(const ushortT* __restrict__ A, const ushortT* __restrict__ B,
                        const float* __restrict__ bias, TC* __restrict__ C,
                        int K, int lda, int ldb, int ldc,
                        long sA, long sB, long sC, long biasOff, long bzStride,
                        float alpha)
{
    const int t = threadIdx.x;
    const int lane = t & 63, wave = t >> 6;
    const int l15 = lane & 15, quad = lane >> 4;
    const int wr = (wave >> 1) * 64, wc = (wave & 1) * 64;

    const int gx = gridDim.x, gy = gridDim.y;
    const int nwg = gx * gy * (int)gridDim.z;
    const int flat = xcd_swz(blockIdx.x + gx * (blockIdx.y + gy * blockIdx.z), nwg);
    const int bx = flat % gx;
    const int by = (flat / gx) % gy;
    const int bz = flat / (gx * gy);

    const int m0 = by * 128, n0 = bx * 128;
    const long z = bz;

    __shared__ __align__(16) ushortT As[128][64];
    __shared__ __align__(16) ushortT Bs[128][64];

    f32x4 acc[4][4] = {};

    const int sr = t >> 3;
    const int ssw = ((t & 7) ^ (sr & 7)) * 8;
    const ushortT* pA = A + z*sA + (long)(m0 + sr) * lda + ssw;
    const ushortT* pB = B + z*sB + (long)(n0 + sr) * ldb + ssw;
    ushortT* lA = &As[sr][(t & 7) * 8];
    ushortT* lB = &Bs[sr][(t & 7) * 8];

    for (int k0 = 0; k0 < K; k0 += 64) {
#pragma unroll
        for (int i = 0; i < 4; ++i) {
            gld16(pA + (long)i*32*lda + k0, lA + i*32*64);
            gld16(pB + (long)i*32*ldb + k0, lB + i*32*64);
        }
        __syncthreads();
#pragma unroll
        for (int kh = 0; kh < 2; ++kh) {
            const int ca = (kh*32 + quad*8) ^ ((l15 & 7) * 8);
            bf16x8 af[4], bfr[4];
#pragma unroll
            for (int i = 0; i < 4; ++i) {
                af[i]  = *(const bf16x8*)&As[wr + i*16 + l15][ca];
                bfr[i] = *(const bf16x8*)&Bs[wc + i*16 + l15][ca];
            }
#pragma unroll
            for (int mt = 0; mt < 4; ++mt)
#pragma unroll
                for (int nt = 0; nt < 4; ++nt)
                    acc[mt][nt] = __builtin_amdgcn_mfma_f32_16x16x32_bf16(af[mt], bfr[nt], acc[mt][nt], 0, 0, 0);
        }
        __syncthreads();
    }

    TC* Cb = C + z * sC;
#pragma unroll
    for (int nt = 0; nt < 4; ++nt) {
        const int col = n0 + wc + nt*16 + l15;
        const float bv = BIAS ? bias[biasOff + z*bzStride + col] : 0.f;
#pragma unroll
        for (int mt = 0; mt < 4; ++mt) {
#pragma unroll
            for (int r = 0; r < 4; ++r) {
                const int row = m0 + wr + mt*16 + quad*4 + r;
                TC* cp = Cb + (long)row * ldc + col;
                float val = alpha * acc[mt][nt][r] + bv;
                if constexpr (RESID) val += ld1c(cp);
                if constexpr (RELU)  val = fmaxf(val, 0.f);
                st1c(cp, val);
            }
        }
    }
}

// ---------------------------------------------------------------------------
// R10: fused S-gemm + row softmax (validated). Per block: 64 edge rows x
// FULL 256 cols of one batch; writes bf16 P into S_c ushort layout.
// ---------------------------------------------------------------------------
__launch_bounds__(256)
__global__ void sgemm_sm_k(const ushortT* __restrict__ A, const ushortT* __restrict__ B,
                           const float* __restrict__ bvec, float* __restrict__ S,
                           float alpha)
{
    const int t = threadIdx.x;
    const int lane = t & 63, wave = t >> 6;   // wave = column-panel index
    const int l15 = lane & 15, quad = lane >> 4;

    const int gx = gridDim.x;                 // 4 row-blocks of 64
    const int nwg = gx * (int)gridDim.y;
    const int flat = xcd_swz(blockIdx.x + gx * blockIdx.y, nwg);
    const int rb = flat % gx;
    const int z  = flat / gx;

    const int m0 = rb * 64;

    __shared__ __align__(16) ushortT As[64][64];
    __shared__ __align__(16) ushortT Bs[256][64];
    __shared__ float redA[4][64];
    __shared__ float redB[4][64];

    f32x4 acc[4][4] = {};

    const int sr = t >> 3;                    // 0..31 (32 rows per issue)
    const int ssw = ((t & 7) ^ (sr & 7)) * 8;
    const ushortT* pA = A + (long)z*256*1536 + (long)(m0 + sr) * 1536 + ssw;
    const ushortT* pB = B + (long)z*256*1536 + (long)sr * 1536 + ssw;
    ushortT* lA = &As[sr][(t & 7) * 8];
    ushortT* lB = &Bs[sr][(t & 7) * 8];

    for (int k0 = 0; k0 < 1536; k0 += 64) {
        gld16(pA + k0, lA);
        gld16(pA + 32L*1536 + k0, lA + 32*64);
#pragma unroll
        for (int i = 0; i < 8; ++i)
            gld16(pB + (long)i*32*1536 + k0, lB + i*32*64);
        __syncthreads();
#pragma unroll
        for (int kh = 0; kh < 2; ++kh) {
            const int ca = (kh*32 + quad*8) ^ ((l15 & 7) * 8);
            bf16x8 af[4], bfr[4];
#pragma unroll
            for (int i = 0; i < 4; ++i) {
                af[i]  = *(const bf16x8*)&As[i*16 + l15][ca];
                bfr[i] = *(const bf16x8*)&Bs[wave*64 + i*16 + l15][ca];
            }
#pragma unroll
            for (int mt = 0; mt < 4; ++mt)
#pragma unroll
                for (int nt = 0; nt < 4; ++nt)
                    acc[mt][nt] = __builtin_amdgcn_mfma_f32_16x16x32_bf16(af[mt], bfr[nt], acc[mt][nt], 0, 0, 0);
        }
        __syncthreads();
    }

    float bv[4];
#pragma unroll
    for (int nt = 0; nt < 4; ++nt)
        bv[nt] = bvec[z*256 + wave*64 + nt*16 + l15];

    // pass 1: per-row max (64 cols in-wave, then cross-wave via LDS)
#pragma unroll
    for (int mt = 0; mt < 4; ++mt) {
#pragma unroll
        for (int r = 0; r < 4; ++r) {
            float m = -3.4e38f;
#pragma unroll
            for (int nt = 0; nt < 4; ++nt)
                m = fmaxf(m, alpha * acc[mt][nt][r] + bv[nt]);
#pragma unroll
            for (int sh = 1; sh < 16; sh <<= 1)
                m = fmaxf(m, __shfl_xor(m, sh));
            if (l15 == 0) redA[wave][mt*16 + quad*4 + r] = m;
        }
    }
    __syncthreads();
    // pass 2: exp + row sum (exp overwrites acc)
#pragma unroll
    for (int mt = 0; mt < 4; ++mt) {
#pragma unroll
        for (int r = 0; r < 4; ++r) {
            const int lr = mt*16 + quad*4 + r;
            const float mx = fmaxf(fmaxf(redA[0][lr], redA[1][lr]),
                                   fmaxf(redA[2][lr], redA[3][lr]));
            float s = 0.f;
#pragma unroll
            for (int nt = 0; nt < 4; ++nt) {
                const float e = __expf(alpha * acc[mt][nt][r] + bv[nt] - mx);
                acc[mt][nt][r] = e;
                s += e;
            }
#pragma unroll
            for (int sh = 1; sh < 16; sh <<= 1)
                s += __shfl_xor(s, sh);
            if (l15 == 0) redB[wave][lr] = s;
        }
    }
    __syncthreads();
    // pass 3: normalize + write bf16 P (row*512 ushorts, batch stride 131072)
    ushortT* P = (ushortT*)S + (long)z*131072 + (long)m0*512;
#pragma unroll
    for (int mt = 0; mt < 4; ++mt) {
#pragma unroll
        for (int r = 0; r < 4; ++r) {
            const int lr = mt*16 + quad*4 + r;
            const float den = redB[0][lr] + redB[1][lr] + redB[2][lr] + redB[3][lr];
            const float inv = 1.f / den;
#pragma unroll
            for (int nt = 0; nt < 4; ++nt)
                P[(long)lr*512 + wave*64 + nt*16 + l15] = f2bf(acc[mt][nt][r] * inv);
        }
    }
}

// ---------------- block reduction (256 threads) ----------------
__device__ __forceinline__ float blockReduceSum(float v, float* red, int t)
{
    red[t] = v; __syncthreads();
#pragma unroll
    for (int s = 128; s > 0; s >>= 1) {
        if (t < s) red[t] += red[t + s];
        __syncthreads();
    }
    const float r = red[0];
    __syncthreads();
    return r;
}

// ---------------------------------------------------------------------------
// Weight convert / transpose-convert to bf16 fast-path layouts.
// ---------------------------------------------------------------------------
__launch_bounds__(256)
__global__ void convbf_k(const void* __restrict__ in, ushortT* __restrict__ out,
                         long n4, const int* __restrict__ flagp)
{
    const int f = *flagp;
    const long i = (long)blockIdx.x*256 + threadIdx.x;
    if (i >= n4) return;
    const long i0 = i * 4;
    if (f) {
        const float4 v = *(const float4*)((const float*)in + i0);
        ushort4 o; o.x=f2bf(v.x); o.y=f2bf(v.y); o.z=f2bf(v.z); o.w=f2bf(v.w);
        *(ushort4*)(out + i0) = o;
    } else {
        *(ushort4*)(out + i0) = *(const ushort4*)((const ushortT*)in + i0);
    }
}

// R10: 4-way batched 1536x1536 transpose-convert (z selects src/dst pair)
__launch_bounds__(256)
__global__ void tconvbf4_k(const void* __restrict__ i0, const void* __restrict__ i1,
                           const void* __restrict__ i2, const void* __restrict__ i3,
                           ushortT* __restrict__ o0, ushortT* __restrict__ o1,
                           ushortT* __restrict__ o2, ushortT* __restrict__ o3,
                           const int* __restrict__ flagp)
{
    const int f = *flagp;
    const void* in; ushortT* out;
    switch (blockIdx.z) {
        case 0:  in = i0; out = o0; break;
        case 1:  in = i1; out = o1; break;
        case 2:  in = i2; out = o2; break;
        default: in = i3; out = o3; break;
    }
    __shared__ float tile[32][33];
    const int bx = blockIdx.x, by = blockIdx.y;
    const int tx = threadIdx.x & 31, ty = threadIdx.x >> 5;
#pragma unroll
    for (int i = 0; i < 4; ++i) {
        const int k = by*32 + ty + i*8;
        tile[ty + i*8][tx] = get1(in, (long)k*1536 + bx*32 + tx, f);
    }
    __syncthreads();
#pragma unroll
    for (int i = 0; i < 4; ++i) {
        const int n = bx*32 + ty + i*8;
        out[(long)n*1536 + by*32 + tx] = f2bf(tile[tx][ty + i*8]);
    }
}

// R9: transpose-convert [256][512] k-major weight into Wg2T[n][512] at column
// offset koff (fused-gconv2 B operand).
__launch_bounds__(256)
__global__ void tconv512_k(const void* __restrict__ in, ushortT* __restrict__ out,
                           int koff, const int* __restrict__ flagp)
{
    const int f = *flagp;
    __shared__ float tile[32][33];
    const int bx = blockIdx.x, by = blockIdx.y;
    const int tx = threadIdx.x & 31, ty = threadIdx.x >> 5;
#pragma unroll
    for (int i = 0; i < 4; ++i) {
        const int k = by*32 + ty + i*8;
        tile[ty + i*8][tx] = get1(in, (long)k*512 + bx*32 + tx, f);
    }
    __syncthreads();
#pragma unroll
    for (int i = 0; i < 4; ++i) {
        const int n = bx*32 + ty + i*8;
        out[(long)n*512 + koff + by*32 + tx] = f2bf(tile[tx][ty + i*8]);
    }
}

__launch_bounds__(256)
__global__ void convf32_k(const void* __restrict__ in, float* __restrict__ out,
                          int n, const int* __restrict__ flagp)
{
    const int f = *flagp;
    const int i = blockIdx.x*256 + threadIdx.x;
    if (i < n) out[i] = get1(in, i, f);
}

// ---------------------------------------------------------------------------
// R12: ln_head weight precombination. The LN+head dot folds algebraically:
//   p = rs*(sum w1[c]*x[c] - mu*c1) + c2,  w1=lng*hW, c1=sum lng*hW,
//   c2 = sum lnb*hW + headb.
// One block; w1 f32 (vectorizable), c1/c2 scalars -> lnc[0..1].
// ---------------------------------------------------------------------------
__launch_bounds__(256)
__global__ void lnw_k(const void* __restrict__ lng, const void* __restrict__ lnb,
                      const void* __restrict__ hW, const void* __restrict__ hB,
                      float* __restrict__ w1, float* __restrict__ lnc,
                      const int* __restrict__ flagp)
{
    const int fl = *flagp;
    const int t = threadIdx.x;
    __shared__ float red[256];
    float c1p = 0.f, c2p = 0.f;
#pragma unroll
    for (int j = 0; j < 6; ++j) {
        const int col = j*256 + t;
        const float w = get1(hW, col, fl);
        const float g = get1(lng, col, fl);
        const float b = get1(lnb, col, fl);
        w1[col] = g * w;
        c1p += g * w;
        c2p += b * w;
    }
    const float c1 = blockReduceSum(c1p, red, t);
    const float c2 = blockReduceSum(c2p, red, t);
    if (t == 0) { lnc[0] = c1; lnc[1] = c2 + get1(hB, 0, fl); }
}

// ---------------------------------------------------------------------------
// colcomb split (validated): partials + deterministic reduce.
// ---------------------------------------------------------------------------
__launch_bounds__(256)
__global__ void colcomb_part_k(const void* __restrict__ v, int cv, long voff,
                               const void* __restrict__ W, int cW,
                               float* __restrict__ part, const int* __restrict__ flagp)
{
    const int rtf = *flagp;
    const int fv = (cv == C_RT) ? rtf : cv;
    const int fW = (cW == C_RT) ? rtf : cW;
    const int d = blockIdx.x*256 + threadIdx.x;
    const int c0 = blockIdx.y * 24;
    float a = 0.f;
#pragma unroll
    for (int i = 0; i < 24; ++i) {
        const int c = c0 + i;
        a += get1(v, voff + c, fv) * get1(W, (long)c*1536 + d, fW);
    }
    part[blockIdx.y * 1536 + d] = a;
}

__launch_bounds__(256)
__global__ void colcomb_red_k(const float* __restrict__ part,
                              const void* __restrict__ b, int cb,
                              float* __restrict__ out, const int* __restrict__ flagp)
{
    const int rtf = *flagp;
    const int fb = (cb == C_RT) ? rtf : cb;
    const int d = blockIdx.x*256 + threadIdx.x;
    float a = get1(b, d, fb);
#pragma unroll 8
    for (int cy = 0; cy < 64; ++cy) a += part[cy*1536 + d];
    out[d] = a;
}

// ---------------------------------------------------------------------------
// rowdot: out[r] = scale * sum_c bf2f(W[r*1536+c]) * v[c]
// ---------------------------------------------------------------------------
__launch_bounds__(256)
__global__ void rowdot_k(const ushortT* __restrict__ W, const float* __restrict__ v,
                         float* __restrict__ out, float scale)
{
    const int r = blockIdx.x, t = threadIdx.x;
    __shared__ float red[256];
    float p = 0.f;
    for (int c = t; c < 1536; c += 256) p += bf2f(W[(long)r*1536 + c]) * v[c];
    const float tot = blockReduceSum(p, red, t);
    if (t == 0) out[r] = scale * tot;
}

// ---------------------------------------------------------------------------
// gconv1 fused (validated; R10 node-split across blockIdx.y)
// ---------------------------------------------------------------------------
__launch_bounds__(256)
__global__ void gconv1_k(int b0, const void* __restrict__ x, const int* __restrict__ edges,
                         const void* __restrict__ ea,
                         const void* __restrict__ wembW, const void* __restrict__ wembB,
                         const void* __restrict__ Wrel, const void* __restrict__ brel,
                         const void* __restrict__ Wroot, ushortT* __restrict__ ah,
                         const int* __restrict__ flagp)
{
    const int f = *flagp;
    const int bl = blockIdx.x, g = b0 + bl, t = threadIdx.x;
    const int nb0 = blockIdx.y * 32;
    __shared__ float s_x[64][5];
    __shared__ float s_agg[64][5];
    __shared__ int   s_cnt[64];
    __shared__ int   s_off[65];
    __shared__ int   s_src[512];
    __shared__ float s_w[512];

    if (t < 64) s_cnt[t] = 0;
    if (t < 320) s_x[t/5][t%5] = get1(x, (long)(g*64 + t/5)*5 + (t%5), f);
    __syncthreads();

    const float w0 = get1(wembW,0,f), w1 = get1(wembW,1,f), w2 = get1(wembW,2,f);
    const float wb = get1(wembB,0,f);
    int sl[2], dl[2], slot[2]; float wv[2];
#pragma unroll
    for (int e2 = 0; e2 < 2; ++e2) {
        const int e = g*512 + t + 256*e2;
        const int s = edges[e], d = edges[EDIR + e];
        sl[e2] = clampi(s - g*64, 0, 63); dl[e2] = clampi(d - g*64, 0, 63);
        const float a0 = get1(ea, 2L*e, f), a1 = get1(ea, 2L*e+1, f);
        wv[e2] = fmaxf(a0*w0 + ((a1 < 0.5f) ? w1 : w2) + wb, 0.f);
        slot[e2] = atomicAdd(&s_cnt[dl[e2]], 1);
    }
    __syncthreads();
    if (t == 0) {
        int r = 0;
        for (int i = 0; i < 64; ++i) { s_off[i] = r; r += s_cnt[i]; }
        s_off[64] = r;
    }
    __syncthreads();
#pragma unroll
    for (int e2 = 0; e2 < 2; ++e2) {
        const int p = s_off[dl[e2]] + slot[e2];
        s_src[p] = sl[e2]; s_w[p] = wv[e2];
    }
    __syncthreads();
    if (t < 160) {
        const int n = nb0 + t/5, k = t%5;
        float acc = 0.f;
        for (int i = s_off[n]; i < s_off[n+1]; ++i) acc += s_w[i] * s_x[s_src[i]][k];
        s_agg[n][k] = acc;
    }
    __syncthreads();
    float wr[5], wo[5];
#pragma unroll
    for (int k = 0; k < 5; ++k) { wr[k] = get1(Wrel, k*256 + t, f); wo[k] = get1(Wroot, k*256 + t, f); }
    const float bb = get1(brel, t, f);
    for (int n = nb0; n < nb0 + 32; ++n) {
        float v = bb;
#pragma unroll
        for (int k = 0; k < 5; ++k) v += s_agg[n][k]*wr[k] + s_x[n][k]*wo[k];
        ah[(long)(bl*64 + n)*512 + 256 + t] = f2bf(fmaxf(v, 0.f));
    }
}

// ---------------------------------------------------------------------------
// gconv2 aggregation (validated; R10 node-split across blockIdx.y)
// ---------------------------------------------------------------------------
__launch_bounds__(256)
__global__ void gconv2_agg_k(int b0, ushortT* __restrict__ ah, const int* __restrict__ edges,
                             const void* __restrict__ ea,
                             const void* __restrict__ wembW, const void* __restrict__ wembB,
                             const int* __restrict__ flagp)
{
    const int f = *flagp;
    const int bl = blockIdx.x, g = b0 + bl, t = threadIdx.x;
    const int nb0 = blockIdx.y * 32;
    __shared__ int   s_cnt[64];
    __shared__ int   s_off[65];
    __shared__ int   s_src[512];
    __shared__ float s_w[512];

    if (t < 64) s_cnt[t] = 0;
    __syncthreads();

    const float w0 = get1(wembW,0,f), w1 = get1(wembW,1,f), w2 = get1(wembW,2,f);
    const float wb = get1(wembB,0,f);
    int sl[2], dl[2], slot[2]; float wv[2];
#pragma unroll
    for (int e2 = 0; e2 < 2; ++e2) {
        const int e = g*512 + t + 256*e2;
        const int s = edges[e], d = edges[EDIR + e];
        sl[e2] = clampi(s - g*64, 0, 63); dl[e2] = clampi(d - g*64, 0, 63);
        const float a0 = get1(ea, 2L*e, f), a1 = get1(ea, 2L*e+1, f);
        wv[e2] = fmaxf(a0*w0 + ((a1 < 0.5f) ? w1 : w2) + wb, 0.f);
        slot[e2] = atomicAdd(&s_cnt[dl[e2]], 1);
    }
    __syncthreads();
    if (t == 0) {
        int r = 0;
        for (int i = 0; i < 64; ++i) { s_off[i] = r; r += s_cnt[i]; }
        s_off[64] = r;
    }
    __syncthreads();
#pragma unroll
    for (int e2 = 0; e2 < 2; ++e2) {
        const int p = s_off[dl[e2]] + slot[e2];
        s_src[p] = sl[e2]; s_w[p] = wv[e2];
    }
    __syncthreads();
    for (int n = nb0; n < nb0 + 32; ++n) {
        float acc = 0.f;
        const int i0 = s_off[n], i1 = s_off[n+1];
        for (int i = i0; i < i1; ++i)
            acc += s_w[i] * bf2f(ah[(long)(bl*64 + s_src[i])*512 + 256 + t]);
        ah[(long)(bl*64 + n)*512 + t] = f2bf(acc);
    }
}

// ---------------------------------------------------------------------------
// GraphNorm (validated; split across blockIdx.y)
// ---------------------------------------------------------------------------
__launch_bounds__(256)
__global__ void gnorm_k(ushortT* __restrict__ h, const void* __restrict__ gw,
                        const void* __restrict__ gb, const void* __restrict__ gms,
                        const int* __restrict__ flagp)
{
    const int f0 = *flagp;
    const int bl = blockIdx.x, t = threadIdx.x;
    const int f = t + 256*blockIdx.y;
    float acc = 0.f;
    for (int n = 0; n < 64; ++n) acc += bf2f(h[(bl*64+n)*512 + f]);
    const float m2 = get1(gms, f, f0) * (acc * (1.f/64.f));
    float v = 0.f;
    for (int n = 0; n < 64; ++n) { const float d = bf2f(h[(bl*64+n)*512 + f]) - m2; v += d*d; }
    const float rs = rsqrtf(v*(1.f/64.f) + EPSC);
    const float g = get1(gw, f, f0), bb = get1(gb, f, f0);
    for (int n = 0; n < 64; ++n) {
        const int idx = (bl*64+n)*512 + f;
        h[idx] = f2bf(g * (bf2f(h[idx]) - m2) * rs + bb);
    }
}

// ---------------------------------------------------------------------------
// SplitSyndromes sort (unchanged — validated)
// ---------------------------------------------------------------------------
__launch_bounds__(256)
__global__ void sort_k(const int* __restrict__ edges, int* __restrict__ sorted_orig,
                       int* __restrict__ se, int* __restrict__ te)
{
    const int b = blockIdx.x, t = threadIdx.x;
    __shared__ int s_keep[512];
    __shared__ int s_key[512];
    __shared__ int s_ckey[256];
    __shared__ int s_corig[256];
#pragma unroll
    for (int e2 = 0; e2 < 2; ++e2) {
        const int el = t + 256*e2;
        const int e = b*512 + el;
        const int s = edges[e], d = edges[EDIR + e];
        s_keep[el] = (s > d) ? 1 : 0;
        s_key[el]  = ((s - b*64) << 6) | (d - b*64);
    }
    __syncthreads();
#pragma unroll
    for (int e2 = 0; e2 < 2; ++e2) {
        const int el = t + 256*e2;
        if (s_keep[el]) {
            int pos = 0;
            for (int j = 0; j < el; ++j) pos += s_keep[j];
            s_ckey[pos]  = s_key[el];
            s_corig[pos] = b*512 + el;
        }
    }
    __syncthreads();
    const int ki = s_ckey[t];
    int rank = 0;
    for (int j = 0; j < 256; ++j) {
        const int kj = s_ckey[j];
        rank += (kj < ki || (kj == ki && j < t)) ? 1 : 0;
    }
    const int orig = s_corig[t];
    const int p = b*256 + rank;
    sorted_orig[p] = orig;
    se[p] = edges[orig];
    te[p] = edges[EDIR + orig];
}

// ---------------------------------------------------------------------------
// Build F_c + bvec[ge] = F[e] . kb  (unchanged — validated)
// ---------------------------------------------------------------------------
__launch_bounds__(256)
__global__ void fbuild_k(int b0, int maxn, const ushortT* __restrict__ h,
                         const int* __restrict__ sorted_orig,
                         const int* __restrict__ se, const int* __restrict__ te,
                         const void* __restrict__ ea,
                         const void* __restrict__ eW, const void* __restrict__ eB,
                         const float* __restrict__ kb,
                         ushortT* __restrict__ F, float* __restrict__ bvec,
                         const int* __restrict__ flagp)
{
    const int fl = *flagp;
    const int e = blockIdx.x, t = threadIdx.x;
    __shared__ float red[256];
    const int ge = b0*256 + e;
    const int s = clampi(se[ge] - b0*64, 0, maxn);
    const int d = clampi(te[ge] - b0*64, 0, maxn);
    const int orig = clampi(sorted_orig[ge], 0, EDIR-1);
    const float a0 = get1(ea, 2L*orig, fl), a1 = get1(ea, 2L*orig + 1, fl);
    float partial = 0.f;
#pragma unroll
    for (int c = 0; c < 6; ++c) {
        const int col = c*256 + t;
        float v;
        if (c < 2) {
            v = bf2f(h[(long)s*512 + col]);
        } else if (c < 4) {
            const int ff = col - 512;
            v = fmaxf(a0*get1(eW, ff, fl)
                      + ((a1 < 0.5f) ? get1(eW, 512+ff, fl) : get1(eW, 1024+ff, fl))
                      + get1(eB, ff, fl), 0.f);
        } else {
            v = bf2f(h[(long)d*512 + (col - 1024)]);
        }
        F[(long)e*1536 + col] = f2bf(v);
        partial += v * kb[col];
    }
    const float tot = blockReduceSum(partial, red, t);
    if (t == 0) bvec[ge] = tot;
}

// ---------------------------------------------------------------------------
// R12: fused LayerNorm + head dot via precombined weights (lnw_k):
//   gout[e] = rs*(sum w1*x - mu*c1) + c2
// One wave per edge (4/block), zero barriers. Per lane: 3 bf16x8 x-loads +
// 6 float4 w1-loads (all vector); {sum, sumsq, dot} in ONE pass; three
// INDEPENDENT interleaved shfl_xor butterflies. R11's version did 72 scalar
// weight loads/lane (register-starved, serialized at L2 latency) -> 260 us
// at VALUBusy 5%; this removes them entirely.
// ---------------------------------------------------------------------------
__launch_bounds__(256)
__global__ void ln_head_k(int b0, const ushortT* __restrict__ F,
                          const float* __restrict__ w1, const float* __restrict__ lnc,
                          float* __restrict__ gout)
{
    const int t = threadIdx.x;
    const int lane = t & 63, w = t >> 6;
    const long e = (long)blockIdx.x * 4 + w;
    const ushortT* Fr = F + e * 1536;
    const float* wp = w1 + lane*8;

    float s = 0.f, sq = 0.f, d = 0.f;
#pragma unroll
    for (int j = 0; j < 3; ++j) {
        const bf16x8 v = *(const bf16x8*)&Fr[j*512 + lane*8];
        const f32x4 wa = *(const f32x4*)&wp[j*512];
        const f32x4 wb = *(const f32x4*)&wp[j*512 + 4];
#pragma unroll
        for (int jj = 0; jj < 8; ++jj) {
            const float xv = bf2f((ushortT)v[jj]);
            const float wv = (jj < 4) ? wa[jj] : wb[jj-4];
            s += xv; sq += xv*xv; d += wv*xv;
        }
    }
#pragma unroll
    for (int sh = 1; sh < 64; sh <<= 1) {
        s  += __shfl_xor(s, sh);
        sq += __shfl_xor(sq, sh);
        d  += __shfl_xor(d, sh);
    }
    if (lane == 0) {
        const float mu = s * (1.f/1536.f);
        const float var = sq * (1.f/1536.f) - mu*mu;
        const float rs = rsqrtf(var + EPSC);
        gout[b0*256 + e] = rs * (d - mu*lnc[0]) + lnc[1];
    }
}

// ---------------- final output assembly (unchanged — validated) -------------
__launch_bounds__(128)
__global__ void final_k(const float* __restrict__ gout, const int* __restrict__ se,
                        const int* __restrict__ te, const int* __restrict__ sorted_orig,
                        const void* __restrict__ ea, float* __restrict__ out,
                        const int* __restrict__ flagp)
{
    const int fl = *flagp;
    const int b = blockIdx.x, j = threadIdx.x;
    const int e0 = b*256 + 2*j, e1 = e0 + 1;
    const float p0 = gout[e0], p1 = gout[e1];
    const int idx = (p1 < p0) ? 1 : 0;
    const float val = idx ? p1 : p0;
    const int eo = idx ? e1 : e0;
    const int orig = clampi(sorted_orig[eo], 0, EDIR-1);
    const float cls = get1(ea, 2L*orig + 1, fl);
    out[(b*128 + j)*2 + 0] = (float)se[e0];
    out[(b*128 + j)*2 + 1] = (float)te[e0];
    out[32768 + b*128 + j] = val;
    out[32768 + 16384 + b*128 + j] = cls;
}

// ---------------------------------------------------------------------------
// Launch. R12: ln_head via precombined weights (lnw_k in phase-W); everything
// else identical to R11.
// ---------------------------------------------------------------------------
extern "C" void kernel_launch(void* const* d_in, const int* in_sizes, int n_in,
                              void* d_out, int out_size, void* d_ws, size_t ws_size,
                              hipStream_t stream)
{
    (void)out_size;

    const void* x     = d_in[0];
    const int*  edges = (const int*)d_in[1];
    const void* ea    = d_in[2];

    int ws0 = 3;
    while (ws0 < n_in && in_sizes[ws0] != 3) ++ws0;
    if (ws0 + 27 > n_in) ws0 = 5;

    const void* wembW  = d_in[ws0 + 0];
    const void* wembB  = d_in[ws0 + 1];
    const void* g1Wrel = d_in[ws0 + 2];
    const void* g1brel = d_in[ws0 + 3];
    const void* g1Wroot= d_in[ws0 + 4];
    const void* g2Wrel = d_in[ws0 + 5];
    const void* g2brel = d_in[ws0 + 6];
    const void* g2Wroot= d_in[ws0 + 7];
    const void* gnw    = d_in[ws0 + 8];
    const void* gnb    = d_in[ws0 + 9];
    const void* gnms   = d_in[ws0 + 10];
    const void* eembW  = d_in[ws0 + 11];
    const void* eembB  = d_in[ws0 + 12];
    const void* qkvW   = d_in[ws0 + 13];
    const void* qkvb   = d_in[ws0 + 14];
    const void* inWq   = d_in[ws0 + 15];
    const void* inWk   = d_in[ws0 + 16];
    const void* inWv   = d_in[ws0 + 17];
    const void* inbq   = d_in[ws0 + 18];
    // inbk (ws0+19): row-constant score terms -> drop in softmax
    const void* inbv   = d_in[ws0 + 20];
    const void* outW   = d_in[ws0 + 21];
    const void* outb   = d_in[ws0 + 22];
    const void* lng    = d_in[ws0 + 23];
    const void* lnb    = d_in[ws0 + 24];
    const void* headW  = d_in[ws0 + 25];
    const void* headb  = d_in[ws0 + 26];

    char* ws = (char*)d_ws;
    size_t off = 0;
    auto alloc = [&](size_t bytes) {
        void* p = ws + off;
        off = (off + bytes + 255) & ~(size_t)255;
        return p;
    };
    // ---- fixed region (~12 MB) ----
    int*     dflag  = (int*)    alloc(256);
    float*   gout   = (float*)  alloc(EKEEP*4);
    int*     sorted = (int*)    alloc(EKEEP*4);
    int*     seg    = (int*)    alloc(EKEEP*4);
    int*     teg    = (int*)    alloc(EKEEP*4);
    float*   bvec   = (float*)  alloc(EKEEP*4);
    float*   bqc    = (float*)  alloc(1536*4);
    float*   bvc    = (float*)  alloc(1536*4);
    float*   kb     = (float*)  alloc(1536*4);
    float*   bvo    = (float*)  alloc(1536*4);
    float*   g2bf   = (float*)  alloc(512*4);
    float*   lnw    = (float*)  alloc(1536*4);         // R12: lng*hW
    float*   lnc    = (float*)  alloc(256);            // R12: c1, c2+hB
    float*   colpart= (float*)  alloc(64L*1536*4);
    ushortT* Wg2T   = (ushortT*)alloc(512L*512*2);     // fused gconv2 B, [n][k]
    ushortT* MpWv   = (ushortT*)alloc(2L*1536*1536*2); // [Mp^T ; Wvo] contiguous
    ushortT* MpT    = MpWv;                            // Mp^T, [n][k]
    ushortT* Wvo    = MpWv + 1536L*1536;               // Wvo, ROW-major [m][k]
    const size_t fixedB = off;

    // ---- union region (phase-W scratch; overlaps chunk scratch) ----
    const long W2 = 1536L * 1536;
    ushortT* Wqc    = (ushortT*)(ws + fixedB);
    ushortT* Wkc    = Wqc + W2;
    ushortT* Wvc    = Wqc + 2*W2;
    ushortT* outWT  = Wqc + 3*W2;
    ushortT* qkvWbf = Wqc + 4*W2;     // 1536x4608
    ushortT* inWqT  = Wqc + 7*W2;
    ushortT* inWkT  = Wqc + 8*W2;     // adjacent (z=3 B stride = W2)
    ushortT* inWvT  = Wqc + 9*W2;

    // ---- chunk scratch (G=128 guaranteed: perG = 1.97 MB -> ~252 MB) ----
    const size_t perG = 64L*512*2 + 64L*512*2 + 2L*256*1536*2 + 256L*256*4;
    int G = 128;
    while (G > 2 && fixedB + (size_t)G*perG + 65536 > ws_size) G >>= 1;

    size_t coff = fixedB;
    auto calloc2 = [&](size_t bytes) {
        void* p = ws + coff;
        coff = (coff + bytes + 255) & ~(size_t)255;
        return p;
    };
    ushortT* h_c  = (ushortT*)calloc2((size_t)G*64*512*2);
    ushortT* ah_c = (ushortT*)calloc2((size_t)G*64*512*2);   // [ag | h1] K=512
    ushortT* F_c  = (ushortT*)calloc2((size_t)G*256*1536*2);
    ushortT* T_c  = (ushortT*)calloc2((size_t)G*256*1536*2); // T, then V'^T
    float*   S_c  = (float*)  calloc2((size_t)G*256*256*4);  // bf16 P lives here

    const float scale = 0.02551551815399144f;  // 1/sqrt(1536)
    const dim3 blk(256);

    detect_k<<<1, blk, 0, stream>>>((const unsigned int*)x, dflag);
    sort_k<<<128, blk, 0, stream>>>(edges, sorted, seg, teg);

    // ---- phase W ----
    convbf_k<<<(1536*4608/4 + 255)/256, blk, 0, stream>>>(qkvW, qkvWbf, 1536L*4608/4, dflag);
    tconvbf4_k<<<dim3(48,48,4), blk, 0, stream>>>(inWq, inWk, inWv, outW,
                                                  inWqT, inWkT, inWvT, outWT, dflag);
    tconv512_k<<<dim3(16,8), blk, 0, stream>>>(g2Wrel, Wg2T, 0, dflag);
    tconv512_k<<<dim3(16,8), blk, 0, stream>>>(g2Wroot, Wg2T, 256, dflag);
    convf32_k<<<2, blk, 0, stream>>>(g2brel, g2bf, 512, dflag);
    lnw_k<<<1, blk, 0, stream>>>(lng, lnb, headW, headb, lnw, lnc, dflag);
    // (Wqc,Wkc,Wvc) z=3 batch: A = qkvWbf k-slices (sA=1536), B = inW{q,k,v}T
    bgemm_k<ushortT,false,false,false><<<dim3(12,12,3), blk, 0, stream>>>(
        qkvWbf, inWqT, nullptr, Wqc, 1536, 4608, 1536, 1536,
        1536L, W2, W2, 0, 0, 1.f);
    colcomb_part_k<<<dim3(6,64), blk, 0, stream>>>(qkvb, C_RT, 0, inWq, C_RT, colpart, dflag);
    colcomb_red_k<<<6, blk, 0, stream>>>(colpart, inbq, C_RT, bqc, dflag);
    // kb = scale * Wkc @ bqc
    rowdot_k<<<1536, blk, 0, stream>>>(Wkc, bqc, kb, scale);
    colcomb_part_k<<<dim3(6,64), blk, 0, stream>>>(qkvb, C_RT, 3072, inWv, C_RT, colpart, dflag);
    colcomb_red_k<<<6, blk, 0, stream>>>(colpart, inbv, C_RT, bvc, dflag);
    // (MpT, Wvo) z=2 batch, unscaled (scale lives in the S-gemm alpha):
    //   z=0: MpT = Wkc @ Wqc^T
    //   z=1: Wvo = Wvc @ outWT^T = Wvc @ outW   (row-major Wvo)
    bgemm_k<ushortT,false,false,false><<<dim3(12,12,2), blk, 0, stream>>>(
        Wkc, Wqc, nullptr, MpT, 1536, 1536, 1536, 1536,
        W2, 3*W2, W2, 0, 0, 1.f);
    colcomb_part_k<<<dim3(6,64), blk, 0, stream>>>(bvc, C_F32, 0, outW, C_RT, colpart, dflag);
    colcomb_red_k<<<6, blk, 0, stream>>>(colpart, outb, C_RT, bvo, dflag);

    // ---- per-chunk pipeline ----
    const int nchunk = 128 / G;
    const int EC = G * 256;
    for (int c = 0; c < nchunk; ++c) {
        const int b0 = c * G;
        const int maxn = G*64 - 1;
        gconv1_k<<<dim3(G,2), blk, 0, stream>>>(b0, x, edges, ea, wembW, wembB,
                                                g1Wrel, g1brel, g1Wroot, ah_c, dflag);
        gconv2_agg_k<<<dim3(G,2), blk, 0, stream>>>(b0, ah_c, edges, ea, wembW, wembB, dflag);
        // h = relu([ag|h1] @ Wg2T^T + g2b)   (fused gconv2, K=512)
        bgemm_k<ushortT,true,false,true><<<dim3(4, G/2, 1), blk, 0, stream>>>(
            ah_c, Wg2T, g2bf, h_c, 512, 512, 512, 512, 0,0,0, 0, 0, 1.f);
        gnorm_k<<<dim3(G,2), blk, 0, stream>>>(h_c, gnw, gnb, gnms, dflag);
        fbuild_k<<<EC, blk, 0, stream>>>(b0, maxn, h_c, sorted, seg, teg, ea,
                                         eembW, eembB, kb, F_c, bvec, dflag);
        // T = F @ Mp^T
        bgemm_k<ushortT,false,false,false><<<dim3(12, EC/128, 1), blk, 0, stream>>>(
            F_c, MpT, nullptr, T_c, 1536, 1536, 1536, 1536, 0,0,0, 0,0, 1.f);
        // P = softmax(scale * T@F^T + bvec)  -> bf16, fused
        sgemm_sm_k<<<dim3(4, G), blk, 0, stream>>>(
            T_c, F_c, bvec + (long)b0*256, S_c, scale);
        // V'^T_b = Wvo @ F_b^T   (into T_c; T dead after S)
        bgemm_k<ushortT,false,false,false><<<dim3(2, 12, G), blk, 0, stream>>>(
            Wvo, F_c, nullptr, T_c, 1536, 1536, 1536, 256,
            0L, 256L*1536, 256L*1536, 0, 0, 1.f);
        // F_b += P_b @ V'_b + bvo   (A = bf16 P in S_c, lda=512 ushorts)
        bgemm_k<ushortT,true,true,false><<<dim3(12, 2, G), blk, 0, stream>>>(
            (const ushortT*)S_c, T_c, bvo, F_c, 256, 512, 256, 1536,
            131072L, 256L*1536, 256L*1536, 0, 0, 1.f);
        ln_head_k<<<EC/4, blk, 0, stream>>>(b0, F_c, lnw, lnc, gout);
    }

    final_k<<<128, dim3(128), 0, stream>>>(gout, seg, teg, sorted, ea, (float*)d_out, dflag);
}